// Round 1
// baseline (1843.836 us; speedup 1.0000x reference)
//
#include <hip/hip_runtime.h>

#define B_ 2
#define S_ 2048
#define H_ 1024
#define NH 16
#define HD 64
#define LN_EPS 1e-5f

typedef unsigned short u16;
typedef unsigned int u32;
typedef __attribute__((ext_vector_type(8))) short bf16x8;
typedef __attribute__((ext_vector_type(4))) float f32x4;
typedef __attribute__((ext_vector_type(4))) u32 u32x4;
typedef __attribute__((ext_vector_type(4))) u16 u16x4;

__device__ __forceinline__ u16 f2bf(float f) {
  u32 u = __float_as_uint(f);
  u32 r = (u + 0x7FFFu + ((u >> 16) & 1u)) >> 16;
  return (u16)r;
}
__device__ __forceinline__ float bflo(u32 w) { return __uint_as_float(w << 16); }
__device__ __forceinline__ float bfhi(u32 w) { return __uint_as_float(w & 0xffff0000u); }

// ---------------- f32 -> bf16 conversion ----------------
__global__ __launch_bounds__(256) void k_cvt(const float* __restrict__ in,
                                             u16* __restrict__ out, int n4) {
  int i = blockIdx.x * 256 + threadIdx.x;
  if (i >= n4) return;
  f32x4 v = ((const f32x4*)in)[i];
  u16x4 o = { f2bf(v[0]), f2bf(v[1]), f2bf(v[2]), f2bf(v[3]) };
  ((u16x4*)out)[i] = o;
}

// ---------------- bf16 GEMM: out[M,N] = A[M,K] @ W[N,K]^T + bias ----------------
// 128x128 tile, BK=64, 4 waves (2x2), each wave 64x64 via 4x4 frags of 16x16x32 MFMA.
// LDS XOR-chunk swizzle: chunk c (16B of 8 bf16) of row r stored at c^(r&7).
template<int RELU, int F32OUT, int BF16OUT>
__global__ __launch_bounds__(256) void k_gemm(const u16* __restrict__ A,
                                              const u16* __restrict__ W,
                                              const float* __restrict__ bias,
                                              float* __restrict__ outf,
                                              u16* __restrict__ outb,
                                              int M, int N, int K) {
  __shared__ u16 As[128 * 64];
  __shared__ u16 Bs[128 * 64];
  const int tid = threadIdx.x;
  const int lane = tid & 63;
  const int wid = tid >> 6;
  const int wm = wid >> 1, wn = wid & 1;
  const int row0 = blockIdx.y * 128, col0 = blockIdx.x * 128;
  const int lr = lane & 15, lk = lane >> 4;

  f32x4 acc[4][4];
#pragma unroll
  for (int i = 0; i < 4; ++i)
#pragma unroll
    for (int j = 0; j < 4; ++j) acc[i][j] = (f32x4){0.f, 0.f, 0.f, 0.f};

  for (int kt = 0; kt < K; kt += 64) {
#pragma unroll
    for (int p = 0; p < 4; ++p) {
      int id = p * 256 + tid;
      int r = id >> 3, c = id & 7;
      u32x4 av = *(const u32x4*)(A + (size_t)(row0 + r) * K + kt + c * 8);
      *(u32x4*)(As + r * 64 + ((c ^ (r & 7)) << 3)) = av;
      u32x4 bv = *(const u32x4*)(W + (size_t)(col0 + r) * K + kt + c * 8);
      *(u32x4*)(Bs + r * 64 + ((c ^ (r & 7)) << 3)) = bv;
    }
    __syncthreads();
#pragma unroll
    for (int ks = 0; ks < 2; ++ks) {
      bf16x8 af[4], bfr[4];
#pragma unroll
      for (int mi = 0; mi < 4; ++mi) {
        int r = wm * 64 + mi * 16 + lr;
        af[mi] = *(const bf16x8*)(As + r * 64 + (((ks * 4 + lk) ^ (r & 7)) << 3));
      }
#pragma unroll
      for (int ni = 0; ni < 4; ++ni) {
        int r = wn * 64 + ni * 16 + lr;
        bfr[ni] = *(const bf16x8*)(Bs + r * 64 + (((ks * 4 + lk) ^ (r & 7)) << 3));
      }
#pragma unroll
      for (int mi = 0; mi < 4; ++mi)
#pragma unroll
        for (int ni = 0; ni < 4; ++ni)
          acc[mi][ni] = __builtin_amdgcn_mfma_f32_16x16x32_bf16(af[mi], bfr[ni],
                                                                acc[mi][ni], 0, 0, 0);
    }
    __syncthreads();
  }

#pragma unroll
  for (int mi = 0; mi < 4; ++mi) {
#pragma unroll
    for (int ni = 0; ni < 4; ++ni) {
#pragma unroll
      for (int r = 0; r < 4; ++r) {
        int row = row0 + wm * 64 + mi * 16 + lk * 4 + r;
        int col = col0 + wn * 64 + ni * 16 + lr;
        float v = acc[mi][ni][r] + bias[col];
        if (RELU) v = fmaxf(v, 0.f);
        if (F32OUT) outf[(size_t)row * N + col] = v;
        if (BF16OUT) outb[(size_t)row * N + col] = f2bf(v);
      }
    }
  }
}

// ---------------- flash attention (causal), 1 thread = 1 query row ----------------
// grid: (S/256, B*NH); block 256. K/V tiles 64x64 staged to LDS as f32.
__global__ __launch_bounds__(256) void k_attn(const u16* __restrict__ Q,
                                              const u16* __restrict__ Kg,
                                              const u16* __restrict__ Vg,
                                              u16* __restrict__ mid) {
  __shared__ float Ks[64][64];
  __shared__ float Vs[64][64];
  const int tid = threadIdx.x;
  const int qb = blockIdx.x;
  const int bh = blockIdx.y;
  const int b = bh >> 4, h = bh & 15;
  const int qi = qb * 256 + tid;
  const size_t qoff = ((size_t)(b * S_ + qi)) * H_ + h * HD;

  float q[64];
#pragma unroll
  for (int c = 0; c < 8; ++c) {
    u32x4 u = *(const u32x4*)(Q + qoff + c * 8);
#pragma unroll
    for (int t = 0; t < 4; ++t) {
      q[c * 8 + t * 2]     = bflo(u[t]) * 0.125f;
      q[c * 8 + t * 2 + 1] = bfhi(u[t]) * 0.125f;
    }
  }

  float m = -1e30f, l = 0.f;
  float acc[64];
#pragma unroll
  for (int d = 0; d < 64; ++d) acc[d] = 0.f;

  const int kbmax = (qb * 256 + 255) >> 6;
  for (int kb = 0; kb <= kbmax; ++kb) {
    __syncthreads();
#pragma unroll
    for (int p = 0; p < 2; ++p) {
      int id = p * 256 + tid;
      int r = id >> 3, c = id & 7;
      size_t off = ((size_t)(b * S_ + kb * 64 + r)) * H_ + h * HD + c * 8;
      u32x4 ku = *(const u32x4*)(Kg + off);
      u32x4 vu = *(const u32x4*)(Vg + off);
      f32x4 k0, k1, v0, v1;
#pragma unroll
      for (int t = 0; t < 2; ++t) {
        k0[t * 2] = bflo(ku[t]);     k0[t * 2 + 1] = bfhi(ku[t]);
        k1[t * 2] = bflo(ku[t + 2]); k1[t * 2 + 1] = bfhi(ku[t + 2]);
        v0[t * 2] = bflo(vu[t]);     v0[t * 2 + 1] = bfhi(vu[t]);
        v1[t * 2] = bflo(vu[t + 2]); v1[t * 2 + 1] = bfhi(vu[t + 2]);
      }
      *(f32x4*)(&Ks[r][c * 8]) = k0;
      *(f32x4*)(&Ks[r][c * 8 + 4]) = k1;
      *(f32x4*)(&Vs[r][c * 8]) = v0;
      *(f32x4*)(&Vs[r][c * 8 + 4]) = v1;
    }
    __syncthreads();

#pragma unroll 1
    for (int jc = 0; jc < 4; ++jc) {
      float s16[16];
#pragma unroll
      for (int jj = 0; jj < 16; ++jj) {
        const f32x4* kr = (const f32x4*)&Ks[jc * 16 + jj][0];
        float sj = 0.f;
#pragma unroll
        for (int d4 = 0; d4 < 16; ++d4) {
          f32x4 kv = kr[d4];
          sj = fmaf(q[d4 * 4 + 0], kv[0], sj);
          sj = fmaf(q[d4 * 4 + 1], kv[1], sj);
          sj = fmaf(q[d4 * 4 + 2], kv[2], sj);
          sj = fmaf(q[d4 * 4 + 3], kv[3], sj);
        }
        int kvj = kb * 64 + jc * 16 + jj;
        s16[jj] = (kvj <= qi) ? sj : -1e30f;
      }
      float bm = s16[0];
#pragma unroll
      for (int jj = 1; jj < 16; ++jj) bm = fmaxf(bm, s16[jj]);
      float mn = fmaxf(m, bm);
      float corr = __expf(m - mn);
      m = mn;
      l *= corr;
#pragma unroll
      for (int d = 0; d < 64; ++d) acc[d] *= corr;
#pragma unroll
      for (int jj = 0; jj < 16; ++jj) {
        float p = __expf(s16[jj] - mn);
        l += p;
        const f32x4* vr = (const f32x4*)&Vs[jc * 16 + jj][0];
#pragma unroll
        for (int d4 = 0; d4 < 16; ++d4) {
          f32x4 vv = vr[d4];
          acc[d4 * 4 + 0] = fmaf(p, vv[0], acc[d4 * 4 + 0]);
          acc[d4 * 4 + 1] = fmaf(p, vv[1], acc[d4 * 4 + 1]);
          acc[d4 * 4 + 2] = fmaf(p, vv[2], acc[d4 * 4 + 2]);
          acc[d4 * 4 + 3] = fmaf(p, vv[3], acc[d4 * 4 + 3]);
        }
      }
    }
  }

  float inv = 1.f / l;
#pragma unroll
  for (int c = 0; c < 8; ++c) {
    u32x4 pk;
#pragma unroll
    for (int t = 0; t < 4; ++t) {
      u32 lo = (u32)f2bf(acc[c * 8 + t * 2] * inv);
      u32 hi = (u32)f2bf(acc[c * 8 + t * 2 + 1] * inv);
      pk[t] = lo | (hi << 16);
    }
    *(u32x4*)(mid + qoff + c * 8) = pk;
  }
}

// ---------------- fused residual + LayerNorm ----------------
// t = a + r (per row of H=1024); out = (t - mu) * rsqrt(var + eps) * g + b
template<int BF16OUT>
__global__ __launch_bounds__(256) void k_ln(const float* __restrict__ a,
                                            const float* __restrict__ r,
                                            const float* __restrict__ g,
                                            const float* __restrict__ bb,
                                            float* __restrict__ outf,
                                            u16* __restrict__ outb) {
  __shared__ float red[8];
  const int row = blockIdx.x, tid = threadIdx.x;
  const size_t base = (size_t)row * H_ + tid * 4;
  f32x4 va = *(const f32x4*)(a + base);
  f32x4 vr = *(const f32x4*)(r + base);
  f32x4 t = va + vr;
  float sum = t[0] + t[1] + t[2] + t[3];
#pragma unroll
  for (int msk = 32; msk >= 1; msk >>= 1) sum += __shfl_xor(sum, msk, 64);
  if ((tid & 63) == 0) red[tid >> 6] = sum;
  __syncthreads();
  float mu = (red[0] + red[1] + red[2] + red[3]) * (1.f / H_);
  f32x4 d = t - mu;
  float sq = d[0] * d[0] + d[1] * d[1] + d[2] * d[2] + d[3] * d[3];
#pragma unroll
  for (int msk = 32; msk >= 1; msk >>= 1) sq += __shfl_xor(sq, msk, 64);
  if ((tid & 63) == 0) red[4 + (tid >> 6)] = sq;
  __syncthreads();
  float var = (red[4] + red[5] + red[6] + red[7]) * (1.f / H_);
  float rs = rsqrtf(var + LN_EPS);
  f32x4 gg = *(const f32x4*)(g + tid * 4);
  f32x4 bv = *(const f32x4*)(bb + tid * 4);
  f32x4 o = d * rs * gg + bv;
  *(f32x4*)(outf + base) = o;
  if (BF16OUT) {
    u16x4 ob = { f2bf(o[0]), f2bf(o[1]), f2bf(o[2]), f2bf(o[3]) };
    *(u16x4*)(outb + base) = ob;
  }
}

// ---------------- host launcher ----------------
extern "C" void kernel_launch(void* const* d_in, const int* in_sizes, int n_in,
                              void* d_out, int out_size, void* d_ws, size_t ws_size,
                              hipStream_t stream) {
  const float* X   = (const float*)d_in[0];
  const float* Wq  = (const float*)d_in[1];
  const float* bq  = (const float*)d_in[2];
  const float* Wk  = (const float*)d_in[3];
  const float* bk  = (const float*)d_in[4];
  const float* Wv  = (const float*)d_in[5];
  const float* bv  = (const float*)d_in[6];
  const float* Wo  = (const float*)d_in[7];
  const float* bo  = (const float*)d_in[8];
  const float* g1  = (const float*)d_in[9];
  const float* b1  = (const float*)d_in[10];
  const float* Wup = (const float*)d_in[11];
  const float* bup = (const float*)d_in[12];
  const float* Wdn = (const float*)d_in[13];
  const float* bdn = (const float*)d_in[14];
  const float* g2  = (const float*)d_in[15];
  const float* b2  = (const float*)d_in[16];
  float* out = (float*)d_out;

  const size_t MS = (size_t)B_ * S_;   // 4096 rows
  const size_t nX = MS * H_;           // 4,194,304

  char* ws = (char*)d_ws;
  size_t off = 0;
  auto alloc = [&](size_t bytes) {
    char* p = ws + off;
    off += (bytes + 255) & ~(size_t)255;
    return p;
  };
  u16* Xb   = (u16*)alloc(nX * 2);
  u16* Wqb  = (u16*)alloc((size_t)H_ * H_ * 2);
  u16* Wkb  = (u16*)alloc((size_t)H_ * H_ * 2);
  u16* Wvb  = (u16*)alloc((size_t)H_ * H_ * 2);
  u16* Wob  = (u16*)alloc((size_t)H_ * H_ * 2);
  u16* Wupb = (u16*)alloc((size_t)4 * H_ * H_ * 2);
  u16* Wdnb = (u16*)alloc((size_t)4 * H_ * H_ * 2);
  u16* Qb   = (u16*)alloc(nX * 2);
  u16* Kb   = (u16*)alloc(nX * 2);
  u16* Vb   = (u16*)alloc(nX * 2);
  u16* midb = (u16*)alloc(nX * 2);
  float* att = (float*)alloc(nX * 4);
  float* h   = (float*)alloc(nX * 4);
  u16* hb    = (u16*)alloc(nX * 2);
  // aliases (consumers finished before producers write):
  u16* upb  = Qb;    // Qb..midb contiguous = 4*8MB = exactly MS*4096 bf16
  float* dwn = att;  // att consumed by LN1 before down GEMM writes

  dim3 blk(256);

  // conversions to bf16
  k_cvt<<<dim3(4096), blk, 0, stream>>>(X, Xb, (int)(nX / 4));
  k_cvt<<<dim3(1024), blk, 0, stream>>>(Wq, Wqb, H_ * H_ / 4);
  k_cvt<<<dim3(1024), blk, 0, stream>>>(Wk, Wkb, H_ * H_ / 4);
  k_cvt<<<dim3(1024), blk, 0, stream>>>(Wv, Wvb, H_ * H_ / 4);
  k_cvt<<<dim3(1024), blk, 0, stream>>>(Wo, Wob, H_ * H_ / 4);
  k_cvt<<<dim3(4096), blk, 0, stream>>>(Wup, Wupb, 4 * H_ * H_ / 4);
  k_cvt<<<dim3(4096), blk, 0, stream>>>(Wdn, Wdnb, 4 * H_ * H_ / 4);

  // QKV projections (bf16 out)
  k_gemm<0, 0, 1><<<dim3(H_ / 128, MS / 128), blk, 0, stream>>>(
      Xb, Wqb, bq, nullptr, Qb, (int)MS, H_, H_);
  k_gemm<0, 0, 1><<<dim3(H_ / 128, MS / 128), blk, 0, stream>>>(
      Xb, Wkb, bk, nullptr, Kb, (int)MS, H_, H_);
  k_gemm<0, 0, 1><<<dim3(H_ / 128, MS / 128), blk, 0, stream>>>(
      Xb, Wvb, bv, nullptr, Vb, (int)MS, H_, H_);

  // causal attention -> mid (bf16)
  k_attn<<<dim3(S_ / 256, B_ * NH), blk, 0, stream>>>(Qb, Kb, Vb, midb);

  // output projection (f32 out)
  k_gemm<0, 1, 0><<<dim3(H_ / 128, MS / 128), blk, 0, stream>>>(
      midb, Wob, bo, att, nullptr, (int)MS, H_, H_);

  // LN1: h = LN(X + att), also bf16 copy
  k_ln<1><<<dim3(MS), blk, 0, stream>>>(X, att, g1, b1, h, hb);

  // MLP up (ReLU, bf16 out)
  k_gemm<1, 0, 1><<<dim3(4 * H_ / 128, MS / 128), blk, 0, stream>>>(
      hb, Wupb, bup, nullptr, upb, (int)MS, 4 * H_, H_);

  // MLP down (f32 out)
  k_gemm<0, 1, 0><<<dim3(H_ / 128, MS / 128), blk, 0, stream>>>(
      upb, Wdnb, bdn, dwn, nullptr, (int)MS, H_, 4 * H_);

  // LN2 -> final output
  k_ln<0><<<dim3(MS), blk, 0, stream>>>(h, dwn, g2, b2, out, nullptr);
}

// Round 2
// 410.111 us; speedup vs baseline: 4.4959x; 4.4959x over previous
//
#include <hip/hip_runtime.h>

#define B_ 2
#define S_ 2048
#define H_ 1024
#define NH 16
#define HD 64
#define LN_EPS 1e-5f

typedef unsigned short u16;
typedef unsigned int u32;
typedef __attribute__((ext_vector_type(8))) short bf16x8;
typedef __attribute__((ext_vector_type(4))) float f32x4;
typedef __attribute__((ext_vector_type(4))) u32 u32x4;
typedef __attribute__((ext_vector_type(4))) u16 u16x4;

__device__ __forceinline__ u16 f2bf(float f) {
  u32 u = __float_as_uint(f);
  u32 r = (u + 0x7FFFu + ((u >> 16) & 1u)) >> 16;
  return (u16)r;
}
__device__ __forceinline__ float bflo(u32 w) { return __uint_as_float(w << 16); }
__device__ __forceinline__ float bfhi(u32 w) { return __uint_as_float(w & 0xffff0000u); }

// ---------------- f32 -> bf16 conversion ----------------
__global__ __launch_bounds__(256) void k_cvt(const float* __restrict__ in,
                                             u16* __restrict__ out, int n4) {
  int i = blockIdx.x * 256 + threadIdx.x;
  if (i >= n4) return;
  f32x4 v = ((const f32x4*)in)[i];
  u16x4 o = { f2bf(v[0]), f2bf(v[1]), f2bf(v[2]), f2bf(v[3]) };
  ((u16x4*)out)[i] = o;
}

// ---------------- bf16 GEMM: out[M,N] = A[M,K] @ W[N,K]^T + bias ----------------
template<int RELU, int F32OUT, int BF16OUT>
__global__ __launch_bounds__(256) void k_gemm(const u16* __restrict__ A,
                                              const u16* __restrict__ W,
                                              const float* __restrict__ bias,
                                              float* __restrict__ outf,
                                              u16* __restrict__ outb,
                                              int M, int N, int K) {
  __shared__ u16 As[128 * 64];
  __shared__ u16 Bs[128 * 64];
  const int tid = threadIdx.x;
  const int lane = tid & 63;
  const int wid = tid >> 6;
  const int wm = wid >> 1, wn = wid & 1;
  const int row0 = blockIdx.y * 128, col0 = blockIdx.x * 128;
  const int lr = lane & 15, lk = lane >> 4;

  f32x4 acc[4][4];
#pragma unroll
  for (int i = 0; i < 4; ++i)
#pragma unroll
    for (int j = 0; j < 4; ++j) acc[i][j] = (f32x4){0.f, 0.f, 0.f, 0.f};

  for (int kt = 0; kt < K; kt += 64) {
#pragma unroll
    for (int p = 0; p < 4; ++p) {
      int id = p * 256 + tid;
      int r = id >> 3, c = id & 7;
      u32x4 av = *(const u32x4*)(A + (size_t)(row0 + r) * K + kt + c * 8);
      *(u32x4*)(As + r * 64 + ((c ^ (r & 7)) << 3)) = av;
      u32x4 bv = *(const u32x4*)(W + (size_t)(col0 + r) * K + kt + c * 8);
      *(u32x4*)(Bs + r * 64 + ((c ^ (r & 7)) << 3)) = bv;
    }
    __syncthreads();
#pragma unroll
    for (int ks = 0; ks < 2; ++ks) {
      bf16x8 af[4], bfr[4];
#pragma unroll
      for (int mi = 0; mi < 4; ++mi) {
        int r = wm * 64 + mi * 16 + lr;
        af[mi] = *(const bf16x8*)(As + r * 64 + (((ks * 4 + lk) ^ (r & 7)) << 3));
      }
#pragma unroll
      for (int ni = 0; ni < 4; ++ni) {
        int r = wn * 64 + ni * 16 + lr;
        bfr[ni] = *(const bf16x8*)(Bs + r * 64 + (((ks * 4 + lk) ^ (r & 7)) << 3));
      }
#pragma unroll
      for (int mi = 0; mi < 4; ++mi)
#pragma unroll
        for (int ni = 0; ni < 4; ++ni)
          acc[mi][ni] = __builtin_amdgcn_mfma_f32_16x16x32_bf16(af[mi], bfr[ni],
                                                                acc[mi][ni], 0, 0, 0);
    }
    __syncthreads();
  }

#pragma unroll
  for (int mi = 0; mi < 4; ++mi) {
#pragma unroll
    for (int ni = 0; ni < 4; ++ni) {
#pragma unroll
      for (int r = 0; r < 4; ++r) {
        int row = row0 + wm * 64 + mi * 16 + lk * 4 + r;
        int col = col0 + wn * 64 + ni * 16 + lr;
        float v = acc[mi][ni][r] + bias[col];
        if (RELU) v = fmaxf(v, 0.f);
        if (F32OUT) outf[(size_t)row * N + col] = v;
        if (BF16OUT) outb[(size_t)row * N + col] = f2bf(v);
      }
    }
  }
}

// ---------------- MFMA flash attention (causal) ----------------
// Block: 128 q-rows for one (b,h); 4 waves x 32 q-rows. KV tile = 64.
// K in LDS: row-major [64][64] with XOR chunk swizzle (chunk c of row r at c^(r&7)).
// V in LDS transposed: Vt[d=64][k], row stride 72 elems (16B-aligned, conflict-spread).
// P relayout via per-wave LDS scratch (32x64, same swizzle).
__global__ __launch_bounds__(256) void k_attn_mfma(const u16* __restrict__ Qg,
                                                   const u16* __restrict__ Kg,
                                                   const u16* __restrict__ Vg,
                                                   u16* __restrict__ mid) {
  __shared__ u16 Ks[64 * 64];
  __shared__ u16 Vt[64 * 72];
  __shared__ u16 Ps[4 * 32 * 64];
  const int tid = threadIdx.x, lane = tid & 63, wid = tid >> 6;
  const int qb = blockIdx.x, bh = blockIdx.y;
  const int b = bh >> 4, h = bh & 15;
  const int lr = lane & 15, lg = lane >> 4;
  const int q0w = qb * 128 + wid * 32;
  u16* Pw = Ps + wid * 2048;

  // ---- load Q fragments (scaled by 1/sqrt(64) = 0.125) ----
  union { u32x4 u; bf16x8 b; } qf[2][2];
#pragma unroll
  for (int mf = 0; mf < 2; ++mf)
#pragma unroll
    for (int ks = 0; ks < 2; ++ks) {
      const size_t off = (size_t)(b * S_ + q0w + mf * 16 + lr) * H_ + h * HD + ks * 32 + lg * 8;
      u32x4 u = *(const u32x4*)(Qg + off);
      u32x4 s;
#pragma unroll
      for (int t = 0; t < 4; ++t) {
        u32 lo = (u32)f2bf(bflo(u[t]) * 0.125f);
        u32 hi = (u32)f2bf(bfhi(u[t]) * 0.125f);
        s[t] = lo | (hi << 16);
      }
      qf[mf][ks].u = s;
    }

  float mst[2][4], lst[2][4];
  f32x4 acc[2][4];
#pragma unroll
  for (int mf = 0; mf < 2; ++mf) {
#pragma unroll
    for (int r = 0; r < 4; ++r) { mst[mf][r] = -1e30f; lst[mf][r] = 0.f; }
#pragma unroll
    for (int nf = 0; nf < 4; ++nf) acc[mf][nf] = (f32x4){0.f, 0.f, 0.f, 0.f};
  }

  const int nt = qb * 2 + 2;
  for (int kv = 0; kv < nt; ++kv) {
    __syncthreads();
    // ---- stage K (swizzled) and V^T (padded) ----
#pragma unroll
    for (int p = 0; p < 2; ++p) {
      int id = p * 256 + tid;
      int r = id >> 3, c = id & 7;
      size_t off = (size_t)(b * S_ + kv * 64 + r) * H_ + h * HD + c * 8;
      u32x4 ku = *(const u32x4*)(Kg + off);
      *(u32x4*)(Ks + r * 64 + ((c ^ (r & 7)) << 3)) = ku;
      u32x4 vu = *(const u32x4*)(Vg + off);
#pragma unroll
      for (int e = 0; e < 8; ++e) {
        u16 val = (u16)(vu[e >> 1] >> ((e & 1) * 16));
        Vt[(c * 8 + e) * 72 + r] = val;
      }
    }
    __syncthreads();

    if (kv * 64 > q0w + 31) continue;  // fully masked for this wave

    // ---- S = Q @ K^T ----
    f32x4 sf[2][4];
#pragma unroll
    for (int mf = 0; mf < 2; ++mf)
#pragma unroll
      for (int nf = 0; nf < 4; ++nf) sf[mf][nf] = (f32x4){0.f, 0.f, 0.f, 0.f};
#pragma unroll
    for (int ks = 0; ks < 2; ++ks) {
      bf16x8 kf[4];
#pragma unroll
      for (int nf = 0; nf < 4; ++nf) {
        int r = nf * 16 + lr;
        kf[nf] = *(const bf16x8*)(Ks + r * 64 + (((ks * 4 + lg) ^ (r & 7)) << 3));
      }
#pragma unroll
      for (int mf = 0; mf < 2; ++mf)
#pragma unroll
        for (int nf = 0; nf < 4; ++nf)
          sf[mf][nf] = __builtin_amdgcn_mfma_f32_16x16x32_bf16(qf[mf][ks].b, kf[nf],
                                                               sf[mf][nf], 0, 0, 0);
    }

    // ---- causal mask (boundary tiles only) ----
    if (kv * 64 + 63 > q0w) {
#pragma unroll
      for (int mf = 0; mf < 2; ++mf)
#pragma unroll
        for (int nf = 0; nf < 4; ++nf)
#pragma unroll
          for (int r = 0; r < 4; ++r) {
            int kcol = kv * 64 + nf * 16 + lr;
            int qrow = q0w + mf * 16 + lg * 4 + r;
            if (kcol > qrow) sf[mf][nf][r] = -1e30f;
          }
    }

    // ---- online softmax ----
#pragma unroll
    for (int mf = 0; mf < 2; ++mf) {
      float bm[4], rs[4];
#pragma unroll
      for (int r = 0; r < 4; ++r)
        bm[r] = fmaxf(fmaxf(sf[mf][0][r], sf[mf][1][r]),
                      fmaxf(sf[mf][2][r], sf[mf][3][r]));
#pragma unroll
      for (int r = 0; r < 4; ++r) {
#pragma unroll
        for (int msk = 1; msk <= 8; msk <<= 1)
          bm[r] = fmaxf(bm[r], __shfl_xor(bm[r], msk));
        float mn = fmaxf(mst[mf][r], bm[r]);
        float corr = __expf(mst[mf][r] - mn);
        mst[mf][r] = mn;
        lst[mf][r] *= corr;
#pragma unroll
        for (int nf = 0; nf < 4; ++nf) acc[mf][nf][r] *= corr;
        rs[r] = 0.f;
      }
#pragma unroll
      for (int nf = 0; nf < 4; ++nf)
#pragma unroll
        for (int r = 0; r < 4; ++r) {
          float p = __expf(sf[mf][nf][r] - mst[mf][r]);
          sf[mf][nf][r] = p;
          rs[r] += p;
        }
#pragma unroll
      for (int r = 0; r < 4; ++r) {
#pragma unroll
        for (int msk = 1; msk <= 8; msk <<= 1) rs[r] += __shfl_xor(rs[r], msk);
        lst[mf][r] += rs[r];
      }
    }

    // ---- P -> per-wave LDS (C-layout scatter, swizzled) ----
#pragma unroll
    for (int mf = 0; mf < 2; ++mf)
#pragma unroll
      for (int nf = 0; nf < 4; ++nf)
#pragma unroll
        for (int r = 0; r < 4; ++r) {
          int qq = mf * 16 + lg * 4 + r;
          int kk = nf * 16 + lr;
          int c = (kk >> 3) ^ (qq & 7);
          Pw[qq * 64 + c * 8 + (kk & 7)] = f2bf(sf[mf][nf][r]);
        }

    // ---- O += P @ V  (A = P from LDS, B = V^T from LDS) ----
#pragma unroll
    for (int ks = 0; ks < 2; ++ks) {
      bf16x8 pa[2], vf[4];
#pragma unroll
      for (int mf = 0; mf < 2; ++mf) {
        int r = mf * 16 + lr;
        pa[mf] = *(const bf16x8*)(Pw + r * 64 + (((ks * 4 + lg) ^ (r & 7)) << 3));
      }
#pragma unroll
      for (int nf = 0; nf < 4; ++nf)
        vf[nf] = *(const bf16x8*)(Vt + (nf * 16 + lr) * 72 + ks * 32 + lg * 8);
#pragma unroll
      for (int mf = 0; mf < 2; ++mf)
#pragma unroll
        for (int nf = 0; nf < 4; ++nf)
          acc[mf][nf] = __builtin_amdgcn_mfma_f32_16x16x32_bf16(pa[mf], vf[nf],
                                                                acc[mf][nf], 0, 0, 0);
    }
  }

  // ---- epilogue: O / l -> mid (bf16) ----
#pragma unroll
  for (int mf = 0; mf < 2; ++mf) {
    float inv[4];
#pragma unroll
    for (int r = 0; r < 4; ++r) inv[r] = 1.f / lst[mf][r];
#pragma unroll
    for (int nf = 0; nf < 4; ++nf)
#pragma unroll
      for (int r = 0; r < 4; ++r) {
        int q = q0w + mf * 16 + lg * 4 + r;
        int d = nf * 16 + lr;
        mid[(size_t)(b * S_ + q) * H_ + h * HD + d] = f2bf(acc[mf][nf][r] * inv[r]);
      }
  }
}

// ---------------- fused residual + LayerNorm ----------------
template<int BF16OUT>
__global__ __launch_bounds__(256) void k_ln(const float* __restrict__ a,
                                            const float* __restrict__ r,
                                            const float* __restrict__ g,
                                            const float* __restrict__ bb,
                                            float* __restrict__ outf,
                                            u16* __restrict__ outb) {
  __shared__ float red[8];
  const int row = blockIdx.x, tid = threadIdx.x;
  const size_t base = (size_t)row * H_ + tid * 4;
  f32x4 va = *(const f32x4*)(a + base);
  f32x4 vr = *(const f32x4*)(r + base);
  f32x4 t = va + vr;
  float sum = t[0] + t[1] + t[2] + t[3];
#pragma unroll
  for (int msk = 32; msk >= 1; msk >>= 1) sum += __shfl_xor(sum, msk, 64);
  if ((tid & 63) == 0) red[tid >> 6] = sum;
  __syncthreads();
  float mu = (red[0] + red[1] + red[2] + red[3]) * (1.f / H_);
  f32x4 d = t - mu;
  float sq = d[0] * d[0] + d[1] * d[1] + d[2] * d[2] + d[3] * d[3];
#pragma unroll
  for (int msk = 32; msk >= 1; msk >>= 1) sq += __shfl_xor(sq, msk, 64);
  if ((tid & 63) == 0) red[4 + (tid >> 6)] = sq;
  __syncthreads();
  float var = (red[4] + red[5] + red[6] + red[7]) * (1.f / H_);
  float rs = rsqrtf(var + LN_EPS);
  f32x4 gg = *(const f32x4*)(g + tid * 4);
  f32x4 bv = *(const f32x4*)(bb + tid * 4);
  f32x4 o = d * rs * gg + bv;
  *(f32x4*)(outf + base) = o;
  if (BF16OUT) {
    u16x4 ob = { f2bf(o[0]), f2bf(o[1]), f2bf(o[2]), f2bf(o[3]) };
    *(u16x4*)(outb + base) = ob;
  }
}

// ---------------- host launcher ----------------
extern "C" void kernel_launch(void* const* d_in, const int* in_sizes, int n_in,
                              void* d_out, int out_size, void* d_ws, size_t ws_size,
                              hipStream_t stream) {
  const float* X   = (const float*)d_in[0];
  const float* Wq  = (const float*)d_in[1];
  const float* bq  = (const float*)d_in[2];
  const float* Wk  = (const float*)d_in[3];
  const float* bk  = (const float*)d_in[4];
  const float* Wv  = (const float*)d_in[5];
  const float* bv  = (const float*)d_in[6];
  const float* Wo  = (const float*)d_in[7];
  const float* bo  = (const float*)d_in[8];
  const float* g1  = (const float*)d_in[9];
  const float* b1  = (const float*)d_in[10];
  const float* Wup = (const float*)d_in[11];
  const float* bup = (const float*)d_in[12];
  const float* Wdn = (const float*)d_in[13];
  const float* bdn = (const float*)d_in[14];
  const float* g2  = (const float*)d_in[15];
  const float* b2  = (const float*)d_in[16];
  float* out = (float*)d_out;

  const size_t MS = (size_t)B_ * S_;   // 4096 rows
  const size_t nX = MS * H_;           // 4,194,304

  char* ws = (char*)d_ws;
  size_t off = 0;
  auto alloc = [&](size_t bytes) {
    char* p = ws + off;
    off += (bytes + 255) & ~(size_t)255;
    return p;
  };
  u16* Xb   = (u16*)alloc(nX * 2);
  u16* Wqb  = (u16*)alloc((size_t)H_ * H_ * 2);
  u16* Wkb  = (u16*)alloc((size_t)H_ * H_ * 2);
  u16* Wvb  = (u16*)alloc((size_t)H_ * H_ * 2);
  u16* Wob  = (u16*)alloc((size_t)H_ * H_ * 2);
  u16* Wupb = (u16*)alloc((size_t)4 * H_ * H_ * 2);
  u16* Wdnb = (u16*)alloc((size_t)4 * H_ * H_ * 2);
  u16* Qb   = (u16*)alloc(nX * 2);
  u16* Kb   = (u16*)alloc(nX * 2);
  u16* Vb   = (u16*)alloc(nX * 2);
  u16* midb = (u16*)alloc(nX * 2);
  float* att = (float*)alloc(nX * 4);
  float* h   = (float*)alloc(nX * 4);
  u16* hb    = (u16*)alloc(nX * 2);
  u16* upb  = Qb;    // Qb..midb contiguous = MS*4096 bf16, reused for MLP-up out
  float* dwn = att;  // att consumed by LN1 before down GEMM writes

  dim3 blk(256);

  k_cvt<<<dim3(4096), blk, 0, stream>>>(X, Xb, (int)(nX / 4));
  k_cvt<<<dim3(1024), blk, 0, stream>>>(Wq, Wqb, H_ * H_ / 4);
  k_cvt<<<dim3(1024), blk, 0, stream>>>(Wk, Wkb, H_ * H_ / 4);
  k_cvt<<<dim3(1024), blk, 0, stream>>>(Wv, Wvb, H_ * H_ / 4);
  k_cvt<<<dim3(1024), blk, 0, stream>>>(Wo, Wob, H_ * H_ / 4);
  k_cvt<<<dim3(4096), blk, 0, stream>>>(Wup, Wupb, 4 * H_ * H_ / 4);
  k_cvt<<<dim3(4096), blk, 0, stream>>>(Wdn, Wdnb, 4 * H_ * H_ / 4);

  k_gemm<0, 0, 1><<<dim3(H_ / 128, MS / 128), blk, 0, stream>>>(
      Xb, Wqb, bq, nullptr, Qb, (int)MS, H_, H_);
  k_gemm<0, 0, 1><<<dim3(H_ / 128, MS / 128), blk, 0, stream>>>(
      Xb, Wkb, bk, nullptr, Kb, (int)MS, H_, H_);
  k_gemm<0, 0, 1><<<dim3(H_ / 128, MS / 128), blk, 0, stream>>>(
      Xb, Wvb, bv, nullptr, Vb, (int)MS, H_, H_);

  // causal MFMA flash attention -> mid (bf16)
  k_attn_mfma<<<dim3(S_ / 128, B_ * NH), blk, 0, stream>>>(Qb, Kb, Vb, midb);

  k_gemm<0, 1, 0><<<dim3(H_ / 128, MS / 128), blk, 0, stream>>>(
      midb, Wob, bo, att, nullptr, (int)MS, H_, H_);

  k_ln<1><<<dim3(MS), blk, 0, stream>>>(X, att, g1, b1, h, hb);

  k_gemm<1, 0, 1><<<dim3(4 * H_ / 128, MS / 128), blk, 0, stream>>>(
      hb, Wupb, bup, nullptr, upb, (int)MS, 4 * H_, H_);

  k_gemm<0, 1, 0><<<dim3(H_ / 128, MS / 128), blk, 0, stream>>>(
      upb, Wdnb, bdn, dwn, nullptr, (int)MS, H_, 4 * H_);

  k_ln<0><<<dim3(MS), blk, 0, stream>>>(h, dwn, g2, b2, out, nullptr);
}

// Round 3
// 377.958 us; speedup vs baseline: 4.8784x; 1.0851x over previous
//
#include <hip/hip_runtime.h>

#define B_ 2
#define S_ 2048
#define H_ 1024
#define NH 16
#define HD 64
#define LN_EPS 1e-5f

typedef unsigned short u16;
typedef unsigned int u32;
typedef __attribute__((ext_vector_type(8))) short bf16x8;
typedef __attribute__((ext_vector_type(4))) float f32x4;
typedef __attribute__((ext_vector_type(4))) u32 u32x4;
typedef __attribute__((ext_vector_type(4))) u16 u16x4;

__device__ __forceinline__ u16 f2bf(float f) {
  u32 u = __float_as_uint(f);
  u32 r = (u + 0x7FFFu + ((u >> 16) & 1u)) >> 16;
  return (u16)r;
}
__device__ __forceinline__ float bflo(u32 w) { return __uint_as_float(w << 16); }
__device__ __forceinline__ float bfhi(u32 w) { return __uint_as_float(w & 0xffff0000u); }

// async global->LDS, 16B per lane (CK addrspace-cast idiom)
__device__ __forceinline__ void gload_lds16(const void* g, void* l) {
  __builtin_amdgcn_global_load_lds(
      (const __attribute__((address_space(1))) void*)(uintptr_t)g,
      (__attribute__((address_space(3))) void*)(uintptr_t)l, 16, 0, 0);
}

// ---------------- f32 -> bf16 conversion ----------------
__global__ __launch_bounds__(256) void k_cvt(const float* __restrict__ in,
                                             u16* __restrict__ out, int n4) {
  int i = blockIdx.x * 256 + threadIdx.x;
  if (i >= n4) return;
  f32x4 v = ((const f32x4*)in)[i];
  u16x4 o = { f2bf(v[0]), f2bf(v[1]), f2bf(v[2]), f2bf(v[3]) };
  ((u16x4*)out)[i] = o;
}

// ---------------- pack 3 bias vectors into one [3072] buffer ----------------
__global__ __launch_bounds__(256) void k_pack3(const float* __restrict__ a,
                                               const float* __restrict__ b,
                                               const float* __restrict__ c,
                                               float* __restrict__ o) {
  int i = blockIdx.x * 256 + threadIdx.x;
  if (i >= 3 * H_) return;
  o[i] = (i < H_) ? a[i] : (i < 2 * H_ ? b[i - H_] : c[i - 2 * H_]);
}

// ---------------- bf16 GEMM (m97 structure): out[M,N] = A[M,K] @ W[N,K]^T + bias ----
// 128x128 tile, BK=64, 4 waves (2x2). global_load_lds width-16 staging, linear LDS.
template<int RELU, int F32OUT, int BF16OUT>
__global__ __launch_bounds__(256) void k_gemm(const u16* __restrict__ A,
                                              const u16* __restrict__ W,
                                              const float* __restrict__ bias,
                                              float* __restrict__ outf,
                                              u16* __restrict__ outb,
                                              int M, int N, int K) {
  __shared__ u16 As[128 * 64];
  __shared__ u16 Bs[128 * 64];
  const int tid = threadIdx.x;
  const int lane = tid & 63;
  const int wid = tid >> 6;
  const int wm = wid >> 1, wn = wid & 1;
  const int row0 = blockIdx.y * 128, col0 = blockIdx.x * 128;
  const int lr = lane & 15, lk = lane >> 4;
  const int sr = lane >> 3, sc = lane & 7;  // staging: 8 rows x 8 chunks per issue

  f32x4 acc[4][4];
#pragma unroll
  for (int i = 0; i < 4; ++i)
#pragma unroll
    for (int j = 0; j < 4; ++j) acc[i][j] = (f32x4){0.f, 0.f, 0.f, 0.f};

  for (int kt = 0; kt < K; kt += 64) {
#pragma unroll
    for (int i = 0; i < 4; ++i) {
      const int rbase = 32 * wid + 8 * i;
      const int ldsoff = __builtin_amdgcn_readfirstlane(rbase * 64);
      gload_lds16(A + (size_t)(row0 + rbase + sr) * K + kt + sc * 8, As + ldsoff);
      gload_lds16(W + (size_t)(col0 + rbase + sr) * K + kt + sc * 8, Bs + ldsoff);
    }
    __syncthreads();
#pragma unroll
    for (int ks = 0; ks < 2; ++ks) {
      bf16x8 af[4], bfr[4];
#pragma unroll
      for (int mi = 0; mi < 4; ++mi)
        af[mi] = *(const bf16x8*)(As + (wm * 64 + mi * 16 + lr) * 64 + (ks * 4 + lk) * 8);
#pragma unroll
      for (int ni = 0; ni < 4; ++ni)
        bfr[ni] = *(const bf16x8*)(Bs + (wn * 64 + ni * 16 + lr) * 64 + (ks * 4 + lk) * 8);
#pragma unroll
      for (int mi = 0; mi < 4; ++mi)
#pragma unroll
        for (int ni = 0; ni < 4; ++ni)
          acc[mi][ni] = __builtin_amdgcn_mfma_f32_16x16x32_bf16(af[mi], bfr[ni],
                                                                acc[mi][ni], 0, 0, 0);
    }
    __syncthreads();
  }

#pragma unroll
  for (int mi = 0; mi < 4; ++mi) {
#pragma unroll
    for (int ni = 0; ni < 4; ++ni) {
#pragma unroll
      for (int r = 0; r < 4; ++r) {
        int row = row0 + wm * 64 + mi * 16 + lk * 4 + r;
        int col = col0 + wn * 64 + ni * 16 + lr;
        float v = acc[mi][ni][r] + bias[col];
        if (RELU) v = fmaxf(v, 0.f);
        if (F32OUT) outf[(size_t)row * N + col] = v;
        if (BF16OUT) outb[(size_t)row * N + col] = f2bf(v);
      }
    }
  }
}

// ---------------- V transpose: QKV[(b,s)][2048+h*64+d] -> Vt[bh][d][s] ----------------
__global__ __launch_bounds__(256) void k_vt(const u16* __restrict__ QKV,
                                            u16* __restrict__ vt) {
  __shared__ u16 T[64 * 64];
  const int tid = threadIdx.x;
  const int s0 = blockIdx.x * 64;
  const int bh = blockIdx.y;
  const int b = bh >> 4, h = bh & 15;
#pragma unroll
  for (int p = 0; p < 2; ++p) {
    int id = p * 256 + tid;
    int r = id >> 3, c = id & 7;  // r: s-local, c: d-chunk
    u32x4 v = *(const u32x4*)(QKV + (size_t)(b * S_ + s0 + r) * 3072 + 2048 + h * 64 + c * 8);
    int sw = (r ^ (r >> 3)) & 7;
    *(u32x4*)(T + r * 64 + ((c ^ sw) << 3)) = v;
  }
  __syncthreads();
#pragma unroll
  for (int p = 0; p < 2; ++p) {
    int id = p * 256 + tid;
    int d = id >> 3, cs = id & 7;
    u16 tmp[8];
#pragma unroll
    for (int k = 0; k < 8; ++k) {
      int r = cs * 8 + k;
      int sw = (r ^ (r >> 3)) & 7;
      tmp[k] = T[r * 64 + ((((d >> 3) ^ sw)) << 3) + (d & 7)];
    }
    *(u32x4*)(vt + ((size_t)bh * 64 + d) * 2048 + s0 + cs * 8) = *(const u32x4*)tmp;
  }
}

// ---------------- MFMA flash attention (causal) ----------------
// Block: 128 q-rows, 4 waves x 32 q. KV tile 64. K and V^T staged vectorized+swizzled.
__global__ __launch_bounds__(256) void k_attn_mfma(const u16* __restrict__ QKV,
                                                   const u16* __restrict__ Vt,
                                                   u16* __restrict__ mid) {
  __shared__ u16 Ks[64 * 64];
  __shared__ u16 Vs[64 * 64];
  __shared__ u16 Ps[4 * 32 * 72];
  const int tid = threadIdx.x, lane = tid & 63, wid = tid >> 6;
  const int qb = (S_ / 128 - 1) - blockIdx.x;  // heavy blocks first
  const int bh = blockIdx.y;
  const int b = bh >> 4, h = bh & 15;
  const int lr = lane & 15, lg = lane >> 4;
  const int q0w = qb * 128 + wid * 32;
  u16* Pw = Ps + wid * (32 * 72);

  // Q fragments (x 1/sqrt(64))
  union { u32x4 u; bf16x8 b; } qf[2][2];
#pragma unroll
  for (int mf = 0; mf < 2; ++mf)
#pragma unroll
    for (int ks = 0; ks < 2; ++ks) {
      const size_t off = (size_t)(b * S_ + q0w + mf * 16 + lr) * 3072 + h * HD + ks * 32 + lg * 8;
      u32x4 u = *(const u32x4*)(QKV + off);
      u32x4 s;
#pragma unroll
      for (int t = 0; t < 4; ++t) {
        u32 lo = (u32)f2bf(bflo(u[t]) * 0.125f);
        u32 hi = (u32)f2bf(bfhi(u[t]) * 0.125f);
        s[t] = lo | (hi << 16);
      }
      qf[mf][ks].u = s;
    }

  float mst[2][4], lst[2][4];
  f32x4 acc[2][4];
#pragma unroll
  for (int mf = 0; mf < 2; ++mf) {
#pragma unroll
    for (int r = 0; r < 4; ++r) { mst[mf][r] = -1e30f; lst[mf][r] = 0.f; }
#pragma unroll
    for (int nf = 0; nf < 4; ++nf) acc[mf][nf] = (f32x4){0.f, 0.f, 0.f, 0.f};
  }

  const int nt = qb * 2 + 2;
  for (int kv = 0; kv < nt; ++kv) {
    const int kv0 = kv * 64;
    __syncthreads();
#pragma unroll
    for (int p = 0; p < 2; ++p) {
      int id = p * 256 + tid;
      int r = id >> 3, c = id & 7;
      u32x4 ku = *(const u32x4*)(QKV + (size_t)(b * S_ + kv0 + r) * 3072 + 1024 + h * 64 + c * 8);
      *(u32x4*)(Ks + r * 64 + ((c ^ (r & 7)) << 3)) = ku;
      u32x4 vu = *(const u32x4*)(Vt + ((size_t)bh * 64 + r) * 2048 + kv0 + c * 8);
      *(u32x4*)(Vs + r * 64 + ((c ^ (r & 7)) << 3)) = vu;
    }
    __syncthreads();

    if (kv0 > q0w + 31) continue;  // fully masked for this wave

    // ---- S = Q K^T ----
    f32x4 sf[2][4];
#pragma unroll
    for (int mf = 0; mf < 2; ++mf)
#pragma unroll
      for (int nf = 0; nf < 4; ++nf) sf[mf][nf] = (f32x4){0.f, 0.f, 0.f, 0.f};
#pragma unroll
    for (int ks = 0; ks < 2; ++ks) {
      bf16x8 kf[4];
#pragma unroll
      for (int nf = 0; nf < 4; ++nf) {
        int r = nf * 16 + lr;
        kf[nf] = *(const bf16x8*)(Ks + r * 64 + (((ks * 4 + lg) ^ (r & 7)) << 3));
      }
#pragma unroll
      for (int mf = 0; mf < 2; ++mf)
#pragma unroll
        for (int nf = 0; nf < 4; ++nf)
          sf[mf][nf] = __builtin_amdgcn_mfma_f32_16x16x32_bf16(qf[mf][ks].b, kf[nf],
                                                               sf[mf][nf], 0, 0, 0);
    }

    // ---- causal mask on boundary tiles ----
    if (kv0 + 63 > q0w) {
#pragma unroll
      for (int mf = 0; mf < 2; ++mf)
#pragma unroll
        for (int nf = 0; nf < 4; ++nf)
#pragma unroll
          for (int r = 0; r < 4; ++r) {
            int kcol = kv0 + nf * 16 + lr;
            int qrow = q0w + mf * 16 + lg * 4 + r;
            if (kcol > qrow) sf[mf][nf][r] = -1e30f;
          }
    }

    // ---- online softmax ----
#pragma unroll
    for (int mf = 0; mf < 2; ++mf) {
      float bm[4], rs[4];
#pragma unroll
      for (int r = 0; r < 4; ++r)
        bm[r] = fmaxf(fmaxf(sf[mf][0][r], sf[mf][1][r]),
                      fmaxf(sf[mf][2][r], sf[mf][3][r]));
#pragma unroll
      for (int r = 0; r < 4; ++r) {
#pragma unroll
        for (int msk = 1; msk <= 8; msk <<= 1)
          bm[r] = fmaxf(bm[r], __shfl_xor(bm[r], msk));
        float mn = fmaxf(mst[mf][r], bm[r]);
        float corr = __expf(mst[mf][r] - mn);
        mst[mf][r] = mn;
        lst[mf][r] *= corr;
#pragma unroll
        for (int nf = 0; nf < 4; ++nf) acc[mf][nf][r] *= corr;
        rs[r] = 0.f;
      }
#pragma unroll
      for (int nf = 0; nf < 4; ++nf)
#pragma unroll
        for (int r = 0; r < 4; ++r) {
          float p = __expf(sf[mf][nf][r] - mst[mf][r]);
          sf[mf][nf][r] = p;
          rs[r] += p;
        }
#pragma unroll
      for (int r = 0; r < 4; ++r) {
#pragma unroll
        for (int msk = 1; msk <= 8; msk <<= 1) rs[r] += __shfl_xor(rs[r], msk);
        lst[mf][r] += rs[r];
      }
    }

    // ---- P -> per-wave LDS (stride-72 rows, bank-spread) ----
#pragma unroll
    for (int mf = 0; mf < 2; ++mf)
#pragma unroll
      for (int nf = 0; nf < 4; ++nf)
#pragma unroll
        for (int r = 0; r < 4; ++r) {
          int qq = mf * 16 + lg * 4 + r;
          int kk = nf * 16 + lr;
          Pw[qq * 72 + kk] = f2bf(sf[mf][nf][r]);
        }

    // ---- O += P @ V ----
#pragma unroll
    for (int ks = 0; ks < 2; ++ks) {
      bf16x8 pa[2], vf[4];
#pragma unroll
      for (int mf = 0; mf < 2; ++mf)
        pa[mf] = *(const bf16x8*)(Pw + (mf * 16 + lr) * 72 + (ks * 4 + lg) * 8);
#pragma unroll
      for (int nf = 0; nf < 4; ++nf) {
        int d = nf * 16 + lr;
        vf[nf] = *(const bf16x8*)(Vs + d * 64 + (((ks * 4 + lg) ^ (d & 7)) << 3));
      }
#pragma unroll
      for (int mf = 0; mf < 2; ++mf)
#pragma unroll
        for (int nf = 0; nf < 4; ++nf)
          acc[mf][nf] = __builtin_amdgcn_mfma_f32_16x16x32_bf16(pa[mf], vf[nf],
                                                                acc[mf][nf], 0, 0, 0);
    }
  }

  // ---- epilogue ----
#pragma unroll
  for (int mf = 0; mf < 2; ++mf) {
    float inv[4];
#pragma unroll
    for (int r = 0; r < 4; ++r) inv[r] = 1.f / lst[mf][r];
#pragma unroll
    for (int nf = 0; nf < 4; ++nf)
#pragma unroll
      for (int r = 0; r < 4; ++r) {
        int q = q0w + mf * 16 + lg * 4 + r;
        int d = nf * 16 + lr;
        mid[(size_t)(b * S_ + q) * H_ + h * HD + d] = f2bf(acc[mf][nf][r] * inv[r]);
      }
  }
}

// ---------------- fused residual + LayerNorm ----------------
template<int BF16OUT>
__global__ __launch_bounds__(256) void k_ln(const float* __restrict__ a,
                                            const float* __restrict__ r,
                                            const float* __restrict__ g,
                                            const float* __restrict__ bb,
                                            float* __restrict__ outf,
                                            u16* __restrict__ outb) {
  __shared__ float red[8];
  const int row = blockIdx.x, tid = threadIdx.x;
  const size_t base = (size_t)row * H_ + tid * 4;
  f32x4 va = *(const f32x4*)(a + base);
  f32x4 vr = *(const f32x4*)(r + base);
  f32x4 t = va + vr;
  float sum = t[0] + t[1] + t[2] + t[3];
#pragma unroll
  for (int msk = 32; msk >= 1; msk >>= 1) sum += __shfl_xor(sum, msk, 64);
  if ((tid & 63) == 0) red[tid >> 6] = sum;
  __syncthreads();
  float mu = (red[0] + red[1] + red[2] + red[3]) * (1.f / H_);
  f32x4 d = t - mu;
  float sq = d[0] * d[0] + d[1] * d[1] + d[2] * d[2] + d[3] * d[3];
#pragma unroll
  for (int msk = 32; msk >= 1; msk >>= 1) sq += __shfl_xor(sq, msk, 64);
  if ((tid & 63) == 0) red[4 + (tid >> 6)] = sq;
  __syncthreads();
  float var = (red[4] + red[5] + red[6] + red[7]) * (1.f / H_);
  float rs = rsqrtf(var + LN_EPS);
  f32x4 gg = *(const f32x4*)(g + tid * 4);
  f32x4 bv = *(const f32x4*)(bb + tid * 4);
  f32x4 o = d * rs * gg + bv;
  *(f32x4*)(outf + base) = o;
  if (BF16OUT) {
    u16x4 ob = { f2bf(o[0]), f2bf(o[1]), f2bf(o[2]), f2bf(o[3]) };
    *(u16x4*)(outb + base) = ob;
  }
}

// ---------------- host launcher ----------------
extern "C" void kernel_launch(void* const* d_in, const int* in_sizes, int n_in,
                              void* d_out, int out_size, void* d_ws, size_t ws_size,
                              hipStream_t stream) {
  const float* X   = (const float*)d_in[0];
  const float* Wq  = (const float*)d_in[1];
  const float* bq  = (const float*)d_in[2];
  const float* Wk  = (const float*)d_in[3];
  const float* bk  = (const float*)d_in[4];
  const float* Wv  = (const float*)d_in[5];
  const float* bv  = (const float*)d_in[6];
  const float* Wo  = (const float*)d_in[7];
  const float* bo  = (const float*)d_in[8];
  const float* g1  = (const float*)d_in[9];
  const float* b1  = (const float*)d_in[10];
  const float* Wup = (const float*)d_in[11];
  const float* bup = (const float*)d_in[12];
  const float* Wdn = (const float*)d_in[13];
  const float* bdn = (const float*)d_in[14];
  const float* g2  = (const float*)d_in[15];
  const float* b2  = (const float*)d_in[16];
  float* out = (float*)d_out;

  const size_t MS = (size_t)B_ * S_;   // 4096
  const size_t nX = MS * H_;           // 4,194,304

  char* ws = (char*)d_ws;
  size_t off = 0;
  auto alloc = [&](size_t bytes) {
    char* p = ws + off;
    off += (bytes + 255) & ~(size_t)255;
    return p;
  };
  u16* Xb    = (u16*)alloc(nX * 2);                    // 8MB  (h alias base)
  u16* Wqkv  = (u16*)alloc((size_t)3 * H_ * H_ * 2);   // 6MB
  u16* Wob   = (u16*)alloc((size_t)H_ * H_ * 2);       // 2MB
  u16* Wupb  = (u16*)alloc((size_t)4 * H_ * H_ * 2);   // 8MB
  u16* Wdnb  = (u16*)alloc((size_t)4 * H_ * H_ * 2);   // 8MB
  float* bqkv = (float*)alloc(3 * H_ * 4);             // 12KB
  u16* QKVb  = (u16*)alloc(nX * 3 * 2);                // 24MB (upb alias base)
  u16* midb  = (u16*)alloc(nX * 2);                    // 8MB
  float* att = (float*)alloc(nX * 4);                  // 16MB (vt / dwn alias)
  u16* hb    = (u16*)alloc(nX * 2);                    // 8MB
  // aliases (lifetimes verified: producer runs strictly after consumers of old data)
  float* h   = (float*)Xb;   // 16MB over Xb+Wqkv+Wob (dead after Wo-GEMM)
  u16* upb   = QKVb;         // 32MB over QKVb+midb (dead after attn / Wo-GEMM)
  u16* vtb   = (u16*)att;    // 8MB  (att written by Wo-GEMM after attn reads vtb)
  float* dwn = att;          // down-GEMM output (att consumed by LN1 before)

  dim3 blk(256);

  // conversions
  k_cvt<<<dim3(4096), blk, 0, stream>>>(X, Xb, (int)(nX / 4));
  k_cvt<<<dim3(1024), blk, 0, stream>>>(Wq, Wqkv, H_ * H_ / 4);
  k_cvt<<<dim3(1024), blk, 0, stream>>>(Wk, Wqkv + (size_t)H_ * H_, H_ * H_ / 4);
  k_cvt<<<dim3(1024), blk, 0, stream>>>(Wv, Wqkv + (size_t)2 * H_ * H_, H_ * H_ / 4);
  k_cvt<<<dim3(1024), blk, 0, stream>>>(Wo, Wob, H_ * H_ / 4);
  k_cvt<<<dim3(4096), blk, 0, stream>>>(Wup, Wupb, 4 * H_ * H_ / 4);
  k_cvt<<<dim3(4096), blk, 0, stream>>>(Wdn, Wdnb, 4 * H_ * H_ / 4);
  k_pack3<<<dim3(12), blk, 0, stream>>>(bq, bk, bv, bqkv);

  // fused QKV projection: [4096,3072]
  k_gemm<0, 0, 1><<<dim3(3 * H_ / 128, MS / 128), blk, 0, stream>>>(
      Xb, Wqkv, bqkv, nullptr, QKVb, (int)MS, 3 * H_, H_);

  // V transpose per head
  k_vt<<<dim3(S_ / 64, B_ * NH), blk, 0, stream>>>(QKVb, vtb);

  // causal MFMA flash attention
  k_attn_mfma<<<dim3(S_ / 128, B_ * NH), blk, 0, stream>>>(QKVb, vtb, midb);

  // output projection
  k_gemm<0, 1, 0><<<dim3(H_ / 128, MS / 128), blk, 0, stream>>>(
      midb, Wob, bo, att, nullptr, (int)MS, H_, H_);

  k_ln<1><<<dim3(MS), blk, 0, stream>>>(X, att, g1, b1, h, hb);

  k_gemm<1, 0, 1><<<dim3(4 * H_ / 128, MS / 128), blk, 0, stream>>>(
      hb, Wupb, bup, nullptr, upb, (int)MS, 4 * H_, H_);

  k_gemm<0, 1, 0><<<dim3(H_ / 128, MS / 128), blk, 0, stream>>>(
      upb, Wdnb, bdn, dwn, nullptr, (int)MS, H_, 4 * H_);

  k_ln<0><<<dim3(MS), blk, 0, stream>>>(h, dwn, g2, b2, out, nullptr);
}

// Round 4
// 321.627 us; speedup vs baseline: 5.7328x; 1.1751x over previous
//
#include <hip/hip_runtime.h>

#define B_ 2
#define S_ 2048
#define H_ 1024
#define NH 16
#define HD 64
#define LN_EPS 1e-5f

typedef unsigned short u16;
typedef unsigned int u32;
typedef __attribute__((ext_vector_type(8))) short bf16x8;
typedef __attribute__((ext_vector_type(4))) float f32x4;
typedef __attribute__((ext_vector_type(16))) float f32x16;
typedef __attribute__((ext_vector_type(4))) u32 u32x4;
typedef __attribute__((ext_vector_type(4))) u16 u16x4;

__device__ __forceinline__ u16 f2bf(float f) {
  u32 u = __float_as_uint(f);
  u32 r = (u + 0x7FFFu + ((u >> 16) & 1u)) >> 16;
  return (u16)r;
}
__device__ __forceinline__ float bflo(u32 w) { return __uint_as_float(w << 16); }
__device__ __forceinline__ float bfhi(u32 w) { return __uint_as_float(w & 0xffff0000u); }

// async global->LDS, 16B per lane
__device__ __forceinline__ void gload_lds16(const void* g, void* l) {
  __builtin_amdgcn_global_load_lds(
      (const __attribute__((address_space(1))) void*)(uintptr_t)g,
      (__attribute__((address_space(3))) void*)(uintptr_t)l, 16, 0, 0);
}

// ---------------- f32 -> bf16 conversion ----------------
__global__ __launch_bounds__(256) void k_cvt(const float* __restrict__ in,
                                             u16* __restrict__ out, int n4) {
  int i = blockIdx.x * 256 + threadIdx.x;
  if (i >= n4) return;
  f32x4 v = ((const f32x4*)in)[i];
  u16x4 o = { f2bf(v[0]), f2bf(v[1]), f2bf(v[2]), f2bf(v[3]) };
  ((u16x4*)out)[i] = o;
}

// ---------------- pack 3 bias vectors ----------------
__global__ __launch_bounds__(256) void k_pack3(const float* __restrict__ a,
                                               const float* __restrict__ b,
                                               const float* __restrict__ c,
                                               float* __restrict__ o) {
  int i = blockIdx.x * 256 + threadIdx.x;
  if (i >= 3 * H_) return;
  o[i] = (i < H_) ? a[i] : (i < 2 * H_ ? b[i - H_] : c[i - 2 * H_]);
}

// ---------------- bf16 GEMM (m97 structure), unchanged ----------------
template<int RELU, int F32OUT, int BF16OUT>
__global__ __launch_bounds__(256) void k_gemm(const u16* __restrict__ A,
                                              const u16* __restrict__ W,
                                              const float* __restrict__ bias,
                                              float* __restrict__ outf,
                                              u16* __restrict__ outb,
                                              int M, int N, int K) {
  __shared__ u16 As[128 * 64];
  __shared__ u16 Bs[128 * 64];
  const int tid = threadIdx.x;
  const int lane = tid & 63;
  const int wid = tid >> 6;
  const int wm = wid >> 1, wn = wid & 1;
  const int row0 = blockIdx.y * 128, col0 = blockIdx.x * 128;
  const int lr = lane & 15, lk = lane >> 4;
  const int sr = lane >> 3, sc = lane & 7;

  f32x4 acc[4][4];
#pragma unroll
  for (int i = 0; i < 4; ++i)
#pragma unroll
    for (int j = 0; j < 4; ++j) acc[i][j] = (f32x4){0.f, 0.f, 0.f, 0.f};

  for (int kt = 0; kt < K; kt += 64) {
#pragma unroll
    for (int i = 0; i < 4; ++i) {
      const int rbase = 32 * wid + 8 * i;
      const int ldsoff = __builtin_amdgcn_readfirstlane(rbase * 64);
      gload_lds16(A + (size_t)(row0 + rbase + sr) * K + kt + sc * 8, As + ldsoff);
      gload_lds16(W + (size_t)(col0 + rbase + sr) * K + kt + sc * 8, Bs + ldsoff);
    }
    __syncthreads();
#pragma unroll
    for (int ks = 0; ks < 2; ++ks) {
      bf16x8 af[4], bfr[4];
#pragma unroll
      for (int mi = 0; mi < 4; ++mi)
        af[mi] = *(const bf16x8*)(As + (wm * 64 + mi * 16 + lr) * 64 + (ks * 4 + lk) * 8);
#pragma unroll
      for (int ni = 0; ni < 4; ++ni)
        bfr[ni] = *(const bf16x8*)(Bs + (wn * 64 + ni * 16 + lr) * 64 + (ks * 4 + lk) * 8);
#pragma unroll
      for (int mi = 0; mi < 4; ++mi)
#pragma unroll
        for (int ni = 0; ni < 4; ++ni)
          acc[mi][ni] = __builtin_amdgcn_mfma_f32_16x16x32_bf16(af[mi], bfr[ni],
                                                                acc[mi][ni], 0, 0, 0);
    }
    __syncthreads();
  }

#pragma unroll
  for (int mi = 0; mi < 4; ++mi) {
#pragma unroll
    for (int ni = 0; ni < 4; ++ni) {
#pragma unroll
      for (int r = 0; r < 4; ++r) {
        int row = row0 + wm * 64 + mi * 16 + lk * 4 + r;
        int col = col0 + wn * 64 + ni * 16 + lr;
        float v = acc[mi][ni][r] + bias[col];
        if (RELU) v = fmaxf(v, 0.f);
        if (F32OUT) outf[(size_t)row * N + col] = v;
        if (BF16OUT) outb[(size_t)row * N + col] = f2bf(v);
      }
    }
  }
}

// ---------------- V transpose: QKV[(b,s)][2048+h*64+d] -> Vt[bh][d][s] ----------------
__global__ __launch_bounds__(256) void k_vt(const u16* __restrict__ QKV,
                                            u16* __restrict__ vt) {
  __shared__ u16 T[64 * 64];
  const int tid = threadIdx.x;
  const int s0 = blockIdx.x * 64;
  const int bh = blockIdx.y;
  const int b = bh >> 4, h = bh & 15;
#pragma unroll
  for (int p = 0; p < 2; ++p) {
    int id = p * 256 + tid;
    int r = id >> 3, c = id & 7;
    u32x4 v = *(const u32x4*)(QKV + (size_t)(b * S_ + s0 + r) * 3072 + 2048 + h * 64 + c * 8);
    int sw = (r ^ (r >> 3)) & 7;
    *(u32x4*)(T + r * 64 + ((c ^ sw) << 3)) = v;
  }
  __syncthreads();
#pragma unroll
  for (int p = 0; p < 2; ++p) {
    int id = p * 256 + tid;
    int d = id >> 3, cs = id & 7;
    u16 tmp[8];
#pragma unroll
    for (int k = 0; k < 8; ++k) {
      int r = cs * 8 + k;
      int sw = (r ^ (r >> 3)) & 7;
      tmp[k] = T[r * 64 + ((((d >> 3) ^ sw)) << 3) + (d & 7)];
    }
    *(u32x4*)(vt + ((size_t)bh * 64 + d) * 2048 + s0 + cs * 8) = *(const u32x4*)tmp;
  }
}

// ---------------- MFMA flash attention, swapped-QK^T 32x32 structure ----------------
// Block: 128 q (4 waves x 32 q). Per lane: q = lane&31 owns its full score row.
// S^T = mfma_32x32x16(A=K, B=Q^T); softmax fully in-register (scalar m,l per lane);
// P -> PV B-frag via v_cvt_pk_bf16_f32 + v_permlane32_swap_b32; O^T = V^T @ P^T.
__global__ __launch_bounds__(256, 3) void k_attn_mfma(const u16* __restrict__ QKV,
                                                      const u16* __restrict__ Vt,
                                                      u16* __restrict__ mid) {
  __shared__ u16 lds[9216];  // loop: Ks[4096] + Vs[4096]; epilogue: Ow 4*32*72
  u16* Ks = lds;
  u16* Vs = lds + 4096;
  const int tid = threadIdx.x, lane = tid & 63, wid = tid >> 6;
  const int lq = lane & 31, lh = lane >> 5;
  const int qb = (S_ / 128 - 1) - blockIdx.x;  // heavy blocks first
  const int bh = blockIdx.y;
  const int b = bh >> 4, h = bh & 15;
  const int q0w = qb * 128 + wid * 32;
  const int qg = q0w + lq;

  // ---- Q fragments: qf[ks] holds Q[qg][ks*16 + lh*8 + j] * 0.125 ----
  union U { u32x4 u; bf16x8 b; };
  U qf[4];
#pragma unroll
  for (int ks = 0; ks < 4; ++ks) {
    const size_t off = (size_t)(b * S_ + qg) * 3072 + h * HD + ks * 16 + lh * 8;
    u32x4 u = *(const u32x4*)(QKV + off);
    u32x4 s;
#pragma unroll
    for (int t = 0; t < 4; ++t) {
      u32 lo = (u32)f2bf(bflo(u[t]) * 0.125f);
      u32 hi = (u32)f2bf(bfhi(u[t]) * 0.125f);
      s[t] = lo | (hi << 16);
    }
    qf[ks].u = s;
  }

  float m = -1e30f, l = 0.f;
  f32x16 acc[2];
#pragma unroll
  for (int mo = 0; mo < 2; ++mo)
#pragma unroll
    for (int r = 0; r < 16; ++r) acc[mo][r] = 0.f;

  const int nt = qb * 2 + 2;
  for (int kv = 0; kv < nt; ++kv) {
    const int kv0 = kv * 64;
    __syncthreads();
#pragma unroll
    for (int p = 0; p < 2; ++p) {
      int id = p * 256 + tid;
      int r = id >> 3, c = id & 7;
      u32x4 ku = *(const u32x4*)(QKV + (size_t)(b * S_ + kv0 + r) * 3072 + 1024 + h * 64 + c * 8);
      *(u32x4*)(Ks + r * 64 + ((c ^ (r & 7)) << 3)) = ku;
      u32x4 vu = *(const u32x4*)(Vt + ((size_t)bh * 64 + r) * 2048 + kv0 + c * 8);
      *(u32x4*)(Vs + r * 64 + ((c ^ (r & 7)) << 3)) = vu;
    }
    __syncthreads();

    if (kv0 > q0w + 31) continue;  // fully masked for this wave

    // ---- S^T[kv][q] = K @ Q^T : two 32-row kv blocks ----
    f32x16 sf[2];
#pragma unroll
    for (int nf = 0; nf < 2; ++nf)
#pragma unroll
      for (int r = 0; r < 16; ++r) sf[nf][r] = 0.f;
#pragma unroll
    for (int ks = 0; ks < 4; ++ks) {
#pragma unroll
      for (int nf = 0; nf < 2; ++nf) {
        int r = nf * 32 + lq;
        int c = ks * 2 + lh;
        U kf;
        kf.u = *(const u32x4*)(Ks + r * 64 + ((c ^ (r & 7)) << 3));
        sf[nf] = __builtin_amdgcn_mfma_f32_32x32x16_bf16(kf.b, qf[ks].b, sf[nf], 0, 0, 0);
      }
    }

    // ---- causal mask (boundary tiles): rows = kv, col = q = lane ----
    if (kv0 + 63 > q0w) {
#pragma unroll
      for (int nf = 0; nf < 2; ++nf)
#pragma unroll
        for (int r = 0; r < 16; ++r) {
          int kvg = kv0 + nf * 32 + (r & 3) + 8 * (r >> 2) + 4 * lh;
          if (kvg > qg) sf[nf][r] = -1e30f;
        }
    }

    // ---- in-register online softmax (lane owns q-row; partner lane^32 has other 32 kv) ----
    float tm = sf[0][0];
#pragma unroll
    for (int r = 1; r < 16; ++r) tm = fmaxf(tm, sf[0][r]);
#pragma unroll
    for (int r = 0; r < 16; ++r) tm = fmaxf(tm, sf[1][r]);
    tm = fmaxf(tm, __shfl_xor(tm, 32));
    const float mn = fmaxf(m, tm);
    const float corr = __expf(m - mn);
    m = mn;
    float rs = 0.f;
#pragma unroll
    for (int nf = 0; nf < 2; ++nf)
#pragma unroll
      for (int r = 0; r < 16; ++r) {
        float p = __expf(sf[nf][r] - mn);
        sf[nf][r] = p;
        rs += p;
      }
    rs += __shfl_xor(rs, 32);
    l = l * corr + rs;
#pragma unroll
    for (int mo = 0; mo < 2; ++mo)
#pragma unroll
      for (int r = 0; r < 16; ++r) acc[mo][r] *= corr;

    // ---- P -> packed bf16 pairs ----
    u32 q32[2][8];
#pragma unroll
    for (int nf = 0; nf < 2; ++nf)
#pragma unroll
      for (int i = 0; i < 8; ++i)
        asm("v_cvt_pk_bf16_f32 %0, %1, %2"
            : "=v"(q32[nf][i]) : "v"(sf[nf][2 * i]), "v"(sf[nf][2 * i + 1]));

    // ---- O^T += V^T @ P^T : 4 kv-steps of 16 ----
#pragma unroll
    for (int s = 0; s < 4; ++s) {
      const int nfp = s >> 1, sg = s & 1;
      u32 x = q32[nfp][4 * sg + 0];
      u32 y = q32[nfp][4 * sg + 1];
      u32 z = q32[nfp][4 * sg + 2];
      u32 w = q32[nfp][4 * sg + 3];
      asm("v_permlane32_swap_b32 %0, %1" : "+v"(x), "+v"(z));
      asm("v_permlane32_swap_b32 %0, %1" : "+v"(y), "+v"(w));
      U pb;
      pb.u = (u32x4){x, y, z, w};
#pragma unroll
      for (int mo = 0; mo < 2; ++mo) {
        int r = mo * 32 + lq;
        int c = s * 2 + lh;
        U vv;
        vv.u = *(const u32x4*)(Vs + r * 64 + ((c ^ (r & 7)) << 3));
        acc[mo] = __builtin_amdgcn_mfma_f32_32x32x16_bf16(vv.b, pb.b, acc[mo], 0, 0, 0);
      }
    }
  }

  // ---- epilogue: O^T/l -> LDS transpose -> coalesced store ----
  __syncthreads();  // all waves done with Ks/Vs
  u16* Ow = lds + wid * (32 * 72);
  const float inv = 1.f / l;
#pragma unroll
  for (int mo = 0; mo < 2; ++mo)
#pragma unroll
    for (int r = 0; r < 16; ++r) {
      int d = mo * 32 + (r & 3) + 8 * (r >> 2) + 4 * lh;
      Ow[lq * 72 + d] = f2bf(acc[mo][r] * inv);
    }
  __asm__ volatile("" ::: "memory");
#pragma unroll
  for (int r4 = 0; r4 < 4; ++r4) {
    int ql = r4 * 8 + (lane >> 3);
    int c = lane & 7;
    u32x4 v = *(const u32x4*)(Ow + ql * 72 + c * 8);
    *(u32x4*)(mid + (size_t)(b * S_ + q0w + ql) * H_ + h * HD + c * 8) = v;
  }
}

// ---------------- fused residual + LayerNorm ----------------
template<int BF16OUT>
__global__ __launch_bounds__(256) void k_ln(const float* __restrict__ a,
                                            const float* __restrict__ r,
                                            const float* __restrict__ g,
                                            const float* __restrict__ bb,
                                            float* __restrict__ outf,
                                            u16* __restrict__ outb) {
  __shared__ float red[8];
  const int row = blockIdx.x, tid = threadIdx.x;
  const size_t base = (size_t)row * H_ + tid * 4;
  f32x4 va = *(const f32x4*)(a + base);
  f32x4 vr = *(const f32x4*)(r + base);
  f32x4 t = va + vr;
  float sum = t[0] + t[1] + t[2] + t[3];
#pragma unroll
  for (int msk = 32; msk >= 1; msk >>= 1) sum += __shfl_xor(sum, msk, 64);
  if ((tid & 63) == 0) red[tid >> 6] = sum;
  __syncthreads();
  float mu = (red[0] + red[1] + red[2] + red[3]) * (1.f / H_);
  f32x4 d = t - mu;
  float sq = d[0] * d[0] + d[1] * d[1] + d[2] * d[2] + d[3] * d[3];
#pragma unroll
  for (int msk = 32; msk >= 1; msk >>= 1) sq += __shfl_xor(sq, msk, 64);
  if ((tid & 63) == 0) red[4 + (tid >> 6)] = sq;
  __syncthreads();
  float var = (red[4] + red[5] + red[6] + red[7]) * (1.f / H_);
  float rs = rsqrtf(var + LN_EPS);
  f32x4 gg = *(const f32x4*)(g + tid * 4);
  f32x4 bv = *(const f32x4*)(bb + tid * 4);
  f32x4 o = d * rs * gg + bv;
  *(f32x4*)(outf + base) = o;
  if (BF16OUT) {
    u16x4 ob = { f2bf(o[0]), f2bf(o[1]), f2bf(o[2]), f2bf(o[3]) };
    *(u16x4*)(outb + base) = ob;
  }
}

// ---------------- host launcher ----------------
extern "C" void kernel_launch(void* const* d_in, const int* in_sizes, int n_in,
                              void* d_out, int out_size, void* d_ws, size_t ws_size,
                              hipStream_t stream) {
  const float* X   = (const float*)d_in[0];
  const float* Wq  = (const float*)d_in[1];
  const float* bq  = (const float*)d_in[2];
  const float* Wk  = (const float*)d_in[3];
  const float* bk  = (const float*)d_in[4];
  const float* Wv  = (const float*)d_in[5];
  const float* bv  = (const float*)d_in[6];
  const float* Wo  = (const float*)d_in[7];
  const float* bo  = (const float*)d_in[8];
  const float* g1  = (const float*)d_in[9];
  const float* b1  = (const float*)d_in[10];
  const float* Wup = (const float*)d_in[11];
  const float* bup = (const float*)d_in[12];
  const float* Wdn = (const float*)d_in[13];
  const float* bdn = (const float*)d_in[14];
  const float* g2  = (const float*)d_in[15];
  const float* b2  = (const float*)d_in[16];
  float* out = (float*)d_out;

  const size_t MS = (size_t)B_ * S_;   // 4096
  const size_t nX = MS * H_;           // 4,194,304

  char* ws = (char*)d_ws;
  size_t off = 0;
  auto alloc = [&](size_t bytes) {
    char* p = ws + off;
    off += (bytes + 255) & ~(size_t)255;
    return p;
  };
  u16* Xb    = (u16*)alloc(nX * 2);                    // 8MB  (h alias base)
  u16* Wqkv  = (u16*)alloc((size_t)3 * H_ * H_ * 2);   // 6MB
  u16* Wob   = (u16*)alloc((size_t)H_ * H_ * 2);       // 2MB
  u16* Wupb  = (u16*)alloc((size_t)4 * H_ * H_ * 2);   // 8MB
  u16* Wdnb  = (u16*)alloc((size_t)4 * H_ * H_ * 2);   // 8MB
  float* bqkv = (float*)alloc(3 * H_ * 4);             // 12KB
  u16* QKVb  = (u16*)alloc(nX * 3 * 2);                // 24MB (upb alias base)
  u16* midb  = (u16*)alloc(nX * 2);                    // 8MB
  float* att = (float*)alloc(nX * 4);                  // 16MB (vt / dwn alias)
  u16* hb    = (u16*)alloc(nX * 2);                    // 8MB
  float* h   = (float*)Xb;   // 16MB over Xb+Wqkv+Wob (dead after Wo-GEMM)
  u16* upb   = QKVb;         // 32MB over QKVb+midb (dead after attn / Wo-GEMM)
  u16* vtb   = (u16*)att;    // 8MB  (att written by Wo-GEMM after attn reads vtb)
  float* dwn = att;          // down-GEMM output (att consumed by LN1 before)

  dim3 blk(256);

  k_cvt<<<dim3(4096), blk, 0, stream>>>(X, Xb, (int)(nX / 4));
  k_cvt<<<dim3(1024), blk, 0, stream>>>(Wq, Wqkv, H_ * H_ / 4);
  k_cvt<<<dim3(1024), blk, 0, stream>>>(Wk, Wqkv + (size_t)H_ * H_, H_ * H_ / 4);
  k_cvt<<<dim3(1024), blk, 0, stream>>>(Wv, Wqkv + (size_t)2 * H_ * H_, H_ * H_ / 4);
  k_cvt<<<dim3(1024), blk, 0, stream>>>(Wo, Wob, H_ * H_ / 4);
  k_cvt<<<dim3(4096), blk, 0, stream>>>(Wup, Wupb, 4 * H_ * H_ / 4);
  k_cvt<<<dim3(4096), blk, 0, stream>>>(Wdn, Wdnb, 4 * H_ * H_ / 4);
  k_pack3<<<dim3(12), blk, 0, stream>>>(bq, bk, bv, bqkv);

  k_gemm<0, 0, 1><<<dim3(3 * H_ / 128, MS / 128), blk, 0, stream>>>(
      Xb, Wqkv, bqkv, nullptr, QKVb, (int)MS, 3 * H_, H_);

  k_vt<<<dim3(S_ / 64, B_ * NH), blk, 0, stream>>>(QKVb, vtb);

  k_attn_mfma<<<dim3(S_ / 128, B_ * NH), blk, 0, stream>>>(QKVb, vtb, midb);

  k_gemm<0, 1, 0><<<dim3(H_ / 128, MS / 128), blk, 0, stream>>>(
      midb, Wob, bo, att, nullptr, (int)MS, H_, H_);

  k_ln<1><<<dim3(MS), blk, 0, stream>>>(X, att, g1, b1, h, hb);

  k_gemm<1, 0, 1><<<dim3(4 * H_ / 128, MS / 128), blk, 0, stream>>>(
      hb, Wupb, bup, nullptr, upb, (int)MS, 4 * H_, H_);

  k_gemm<0, 1, 0><<<dim3(H_ / 128, MS / 128), blk, 0, stream>>>(
      upb, Wdnb, bdn, dwn, nullptr, (int)MS, H_, 4 * H_);

  k_ln<0><<<dim3(MS), blk, 0, stream>>>(h, dwn, g2, b2, out, nullptr);
}

// Round 7
// 250.144 us; speedup vs baseline: 7.3711x; 1.2858x over previous
//
#include <hip/hip_runtime.h>

#define B_ 2
#define S_ 2048
#define H_ 1024
#define NH 16
#define HD 64
#define LN_EPS 1e-5f

typedef unsigned short u16;
typedef unsigned int u32;
typedef __attribute__((ext_vector_type(8))) short bf16x8;
typedef __attribute__((ext_vector_type(4))) float f32x4;
typedef __attribute__((ext_vector_type(16))) float f32x16;
typedef __attribute__((ext_vector_type(4))) u32 u32x4;
typedef __attribute__((ext_vector_type(4))) u16 u16x4;

__device__ __forceinline__ u16 f2bf(float f) {
  u32 u = __float_as_uint(f);
  u32 r = (u + 0x7FFFu + ((u >> 16) & 1u)) >> 16;
  return (u16)r;
}
__device__ __forceinline__ float bflo(u32 w) { return __uint_as_float(w << 16); }
__device__ __forceinline__ float bfhi(u32 w) { return __uint_as_float(w & 0xffff0000u); }

// async global->LDS, 16B per lane
__device__ __forceinline__ void gload_lds16(const void* g, void* l) {
  __builtin_amdgcn_global_load_lds(
      (const __attribute__((address_space(1))) void*)(uintptr_t)g,
      (__attribute__((address_space(3))) void*)(uintptr_t)l, 16, 0, 0);
}

// ---------------- f32 -> bf16 conversion ----------------
__global__ __launch_bounds__(256) void k_cvt(const float* __restrict__ in,
                                             u16* __restrict__ out, int n4) {
  int i = blockIdx.x * 256 + threadIdx.x;
  if (i >= n4) return;
  f32x4 v = ((const f32x4*)in)[i];
  u16x4 o = { f2bf(v[0]), f2bf(v[1]), f2bf(v[2]), f2bf(v[3]) };
  ((u16x4*)out)[i] = o;
}

// ---------------- pack 3 bias vectors ----------------
__global__ __launch_bounds__(256) void k_pack3(const float* __restrict__ a,
                                               const float* __restrict__ b,
                                               const float* __restrict__ c,
                                               float* __restrict__ o) {
  int i = blockIdx.x * 256 + threadIdx.x;
  if (i >= 3 * H_) return;
  o[i] = (i < H_) ? a[i] : (i < 2 * H_ ? b[i - H_] : c[i - 2 * H_]);
}

// ============ 256x256 8-phase GEMM, airtight wait schedule ============
// out[M,N] = A[M,K] @ W[N,K]^T (+bias, +relu). 512 thr = 8 waves (2x4).
// BK=64; LDS 128 KiB = 2 slots x (A 256x64 | B 256x64), XOR-chunk swizzle
// via PRE-SWIZZLED GLOBAL SOURCE (linear gload_lds dest) + swizzled ds_read.
// KEY FACT (round-5 bug): every phase reads from ALL FOUR half-tiles of the
// current slot (wr selects A half, wc selects B half, mh/ks are intra-half).
// So tile t+1's staging must be FULLY landed before its ph0. Schedule:
//   ph0 of tile t: issue B0',B1' (4 loads); ph1: issue A0',A1' (4 loads).
//   end of ph3: single s_waitcnt vmcnt(0) (loads issued >=2 phases earlier),
//   then barrier -> slot swap. 7 of 8 barriers/tile have loads in flight.
template<int RELU, int F32OUT, int BF16OUT, int BIAS>
__global__ __launch_bounds__(512, 2) void k_gemm8(const u16* __restrict__ A,
                                                  const u16* __restrict__ W,
                                                  const float* __restrict__ bias,
                                                  float* __restrict__ outf,
                                                  u16* __restrict__ outb,
                                                  int M, int N, int lda, int ldb,
                                                  int Kc, int tilesM) {
  extern __shared__ u16 lds[];
  const int tid = threadIdx.x, lane = tid & 63, wid = tid >> 6;
  const int wr = wid >> 2, wc = wid & 3;
  const int lr = lane & 15, lk = lane >> 4;

  const int nwg = gridDim.x;
  const int bid = blockIdx.x;
  const int lid = (bid & 7) * (nwg >> 3) + (bid >> 3);  // XCD-contiguous chunks
  const int ty = lid % tilesM;
  const int txz = lid / tilesM;
  const int tilesN = N >> 8;
  const int tx = txz % tilesN;
  const int kz = txz / tilesN;
  const int row0 = ty << 8, col0 = tx << 8;
  A += (size_t)kz * Kc;
  W += (size_t)kz * Kc;
  const size_t outoff = (size_t)kz * M * N;

  const int NT = Kc >> 6;

  f32x4 acc[8][4];
#pragma unroll
  for (int i = 0; i < 8; ++i)
#pragma unroll
    for (int j = 0; j < 4; ++j) acc[i][j] = (f32x4){0.f, 0.f, 0.f, 0.f};

  const int srow = tid >> 3;                        // staging row 0..63
  const int csw8 = ((tid & 7) ^ (srow & 7)) << 3;   // pre-swizzled global chunk

  // half-tile ht = 4*t + sel; sel: 0=B.h0, 1=B.h1, 2=A.h0, 3=A.h1
  auto stage_ht = [&](int ht) {
    const int t = ht >> 2, sel = ht & 3;
    const int mat = (sel < 2) ? 1 : 0;   // 1 = B/W
    const int hh = sel & 1;
    const u16* g = mat ? W : A;
    const int ld = mat ? ldb : lda;
    const int b0 = mat ? col0 : row0;
    const int kt = t << 6;
    u16* dst = lds + ((t & 1) << 15) + (mat << 14) + (hh << 13) + tid * 8;
#pragma unroll
    for (int j = 0; j < 2; ++j) {
      const int r = (hh << 7) + (j << 6) + srow;
      gload_lds16(g + (size_t)(b0 + r) * ld + kt + csw8, dst + (j << 12));
    }
  };

  union UU { u32x4 u; bf16x8 b; };
  auto ldvec = [&](const u16* base, int r, int c) -> bf16x8 {
    UU x;
    x.u = *(const u32x4*)(base + r * 64 + ((c ^ (r & 7)) << 3));
    return x.b;
  };

  // prologue: stage tile 0 fully; must all land before ph0 reads
#pragma unroll
  for (int i = 0; i < 4; ++i) stage_ht(i);
  asm volatile("s_waitcnt vmcnt(0)" ::: "memory");
  __builtin_amdgcn_s_barrier();

  for (int t = 0; t < NT; ++t) {
    const u16* SA = lds + ((t & 1) << 15);
    const u16* SB = SA + 16384;
#pragma unroll
    for (int ph = 0; ph < 4; ++ph) {
      const int mh = ph >> 1, ks = ph & 1;
      const int c = (ks << 2) + lk;
      bf16x8 bb[4], aa[4];
#pragma unroll
      for (int ni = 0; ni < 4; ++ni)
        bb[ni] = ldvec(SB, (wc << 6) + (ni << 4) + lr, c);
#pragma unroll
      for (int mi = 0; mi < 4; ++mi)
        aa[mi] = ldvec(SA, (wr << 7) + (mh << 6) + (mi << 4) + lr, c);
      if (t + 1 < NT && ph < 2) {     // issue next tile early: B at ph0, A at ph1
        stage_ht(4 * (t + 1) + 2 * ph);
        stage_ht(4 * (t + 1) + 2 * ph + 1);
      }
      __builtin_amdgcn_s_barrier();
      __builtin_amdgcn_s_setprio(1);
#pragma unroll
      for (int mi = 0; mi < 4; ++mi)
#pragma unroll
        for (int ni = 0; ni < 4; ++ni)
          acc[(mh << 2) + mi][ni] = __builtin_amdgcn_mfma_f32_16x16x32_bf16(
              aa[mi], bb[ni], acc[(mh << 2) + mi][ni], 0, 0, 0);
      __builtin_amdgcn_s_setprio(0);
      if (ph == 3)  // slot swap: next tile's 8 loads (issued ph0/ph1) must be in LDS
        asm volatile("s_waitcnt vmcnt(0)" ::: "memory");
      __builtin_amdgcn_s_barrier();
    }
  }

  // epilogue
  float bs[4] = {0.f, 0.f, 0.f, 0.f};
  if (BIAS) {
#pragma unroll
    for (int ni = 0; ni < 4; ++ni)
      bs[ni] = bias[col0 + (wc << 6) + (ni << 4) + lr];
  }
#pragma unroll
  for (int mi = 0; mi < 8; ++mi) {
#pragma unroll
    for (int ni = 0; ni < 4; ++ni) {
#pragma unroll
      for (int r = 0; r < 4; ++r) {
        int row = row0 + (wr << 7) + (mi << 4) + (lk << 2) + r;
        int col = col0 + (wc << 6) + (ni << 4) + lr;
        float v = acc[mi][ni][r] + bs[ni];
        if (RELU) v = fmaxf(v, 0.f);
        if (F32OUT) outf[outoff + (size_t)row * N + col] = v;
        if (BF16OUT) outb[outoff + (size_t)row * N + col] = f2bf(v);
      }
    }
  }
}

// ---------------- legacy 128x128 GEMM (kept for Wo) ----------------
template<int RELU, int F32OUT, int BF16OUT>
__global__ __launch_bounds__(256) void k_gemm(const u16* __restrict__ A,
                                              const u16* __restrict__ W,
                                              const float* __restrict__ bias,
                                              float* __restrict__ outf,
                                              u16* __restrict__ outb,
                                              int M, int N, int K) {
  __shared__ u16 As[128 * 64];
  __shared__ u16 Bs[128 * 64];
  const int tid = threadIdx.x;
  const int lane = tid & 63;
  const int wid = tid >> 6;
  const int wm = wid >> 1, wn = wid & 1;
  const int row0 = blockIdx.y * 128, col0 = blockIdx.x * 128;
  const int lr = lane & 15, lk = lane >> 4;
  const int sr = lane >> 3, sc = lane & 7;

  f32x4 acc[4][4];
#pragma unroll
  for (int i = 0; i < 4; ++i)
#pragma unroll
    for (int j = 0; j < 4; ++j) acc[i][j] = (f32x4){0.f, 0.f, 0.f, 0.f};

  for (int kt = 0; kt < K; kt += 64) {
#pragma unroll
    for (int i = 0; i < 4; ++i) {
      const int rbase = 32 * wid + 8 * i;
      const int ldsoff = __builtin_amdgcn_readfirstlane(rbase * 64);
      gload_lds16(A + (size_t)(row0 + rbase + sr) * K + kt + sc * 8, As + ldsoff);
      gload_lds16(W + (size_t)(col0 + rbase + sr) * K + kt + sc * 8, Bs + ldsoff);
    }
    __syncthreads();
#pragma unroll
    for (int ks = 0; ks < 2; ++ks) {
      bf16x8 af[4], bfr[4];
#pragma unroll
      for (int mi = 0; mi < 4; ++mi)
        af[mi] = *(const bf16x8*)(As + (wm * 64 + mi * 16 + lr) * 64 + (ks * 4 + lk) * 8);
#pragma unroll
      for (int ni = 0; ni < 4; ++ni)
        bfr[ni] = *(const bf16x8*)(Bs + (wn * 64 + ni * 16 + lr) * 64 + (ks * 4 + lk) * 8);
#pragma unroll
      for (int mi = 0; mi < 4; ++mi)
#pragma unroll
        for (int ni = 0; ni < 4; ++ni)
          acc[mi][ni] = __builtin_amdgcn_mfma_f32_16x16x32_bf16(af[mi], bfr[ni],
                                                                acc[mi][ni], 0, 0, 0);
    }
    __syncthreads();
  }

#pragma unroll
  for (int mi = 0; mi < 4; ++mi) {
#pragma unroll
    for (int ni = 0; ni < 4; ++ni) {
#pragma unroll
      for (int r = 0; r < 4; ++r) {
        int row = row0 + wm * 64 + mi * 16 + lk * 4 + r;
        int col = col0 + wn * 64 + ni * 16 + lr;
        float v = acc[mi][ni][r] + bias[col];
        if (RELU) v = fmaxf(v, 0.f);
        if (F32OUT) outf[(size_t)row * N + col] = v;
        if (BF16OUT) outb[(size_t)row * N + col] = f2bf(v);
      }
    }
  }
}

// ---------------- V transpose: QKV[(b,s)][2048+h*64+d] -> Vt[bh][d][s] ----------------
__global__ __launch_bounds__(256) void k_vt(const u16* __restrict__ QKV,
                                            u16* __restrict__ vt) {
  __shared__ u16 T[64 * 64];
  const int tid = threadIdx.x;
  const int s0 = blockIdx.x * 64;
  const int bh = blockIdx.y;
  const int b = bh >> 4, h = bh & 15;
#pragma unroll
  for (int p = 0; p < 2; ++p) {
    int id = p * 256 + tid;
    int r = id >> 3, c = id & 7;
    u32x4 v = *(const u32x4*)(QKV + (size_t)(b * S_ + s0 + r) * 3072 + 2048 + h * 64 + c * 8);
    int sw = (r ^ (r >> 3)) & 7;
    *(u32x4*)(T + r * 64 + ((c ^ sw) << 3)) = v;
  }
  __syncthreads();
#pragma unroll
  for (int p = 0; p < 2; ++p) {
    int id = p * 256 + tid;
    int d = id >> 3, cs = id & 7;
    u16 tmp[8];
#pragma unroll
    for (int k = 0; k < 8; ++k) {
      int r = cs * 8 + k;
      int sw = (r ^ (r >> 3)) & 7;
      tmp[k] = T[r * 64 + ((((d >> 3) ^ sw)) << 3) + (d & 7)];
    }
    *(u32x4*)(vt + ((size_t)bh * 64 + d) * 2048 + s0 + cs * 8) = *(const u32x4*)tmp;
  }
}

// ---------------- MFMA flash attention, swapped-QK^T 32x32 (unchanged) ----------------
__global__ __launch_bounds__(256, 3) void k_attn_mfma(const u16* __restrict__ QKV,
                                                      const u16* __restrict__ Vt,
                                                      u16* __restrict__ mid) {
  __shared__ u16 lds[9216];
  u16* Ks = lds;
  u16* Vs = lds + 4096;
  const int tid = threadIdx.x, lane = tid & 63, wid = tid >> 6;
  const int lq = lane & 31, lh = lane >> 5;
  const int qb = (S_ / 128 - 1) - blockIdx.x;
  const int bh = blockIdx.y;
  const int b = bh >> 4, h = bh & 15;
  const int q0w = qb * 128 + wid * 32;
  const int qg = q0w + lq;

  union U { u32x4 u; bf16x8 b; };
  U qf[4];
#pragma unroll
  for (int ks = 0; ks < 4; ++ks) {
    const size_t off = (size_t)(b * S_ + qg) * 3072 + h * HD + ks * 16 + lh * 8;
    u32x4 u = *(const u32x4*)(QKV + off);
    u32x4 s;
#pragma unroll
    for (int t = 0; t < 4; ++t) {
      u32 lo = (u32)f2bf(bflo(u[t]) * 0.125f);
      u32 hi = (u32)f2bf(bfhi(u[t]) * 0.125f);
      s[t] = lo | (hi << 16);
    }
    qf[ks].u = s;
  }

  float m = -1e30f, l = 0.f;
  f32x16 acc[2];
#pragma unroll
  for (int mo = 0; mo < 2; ++mo)
#pragma unroll
    for (int r = 0; r < 16; ++r) acc[mo][r] = 0.f;

  const int nt = qb * 2 + 2;
  for (int kv = 0; kv < nt; ++kv) {
    const int kv0 = kv * 64;
    __syncthreads();
#pragma unroll
    for (int p = 0; p < 2; ++p) {
      int id = p * 256 + tid;
      int r = id >> 3, c = id & 7;
      u32x4 ku = *(const u32x4*)(QKV + (size_t)(b * S_ + kv0 + r) * 3072 + 1024 + h * 64 + c * 8);
      *(u32x4*)(Ks + r * 64 + ((c ^ (r & 7)) << 3)) = ku;
      u32x4 vu = *(const u32x4*)(Vt + ((size_t)bh * 64 + r) * 2048 + kv0 + c * 8);
      *(u32x4*)(Vs + r * 64 + ((c ^ (r & 7)) << 3)) = vu;
    }
    __syncthreads();

    if (kv0 > q0w + 31) continue;

    f32x16 sf[2];
#pragma unroll
    for (int nf = 0; nf < 2; ++nf)
#pragma unroll
      for (int r = 0; r < 16; ++r) sf[nf][r] = 0.f;
#pragma unroll
    for (int ks = 0; ks < 4; ++ks) {
#pragma unroll
      for (int nf = 0; nf < 2; ++nf) {
        int r = nf * 32 + lq;
        int c = ks * 2 + lh;
        U kf;
        kf.u = *(const u32x4*)(Ks + r * 64 + ((c ^ (r & 7)) << 3));
        sf[nf] = __builtin_amdgcn_mfma_f32_32x32x16_bf16(kf.b, qf[ks].b, sf[nf], 0, 0, 0);
      }
    }

    if (kv0 + 63 > q0w) {
#pragma unroll
      for (int nf = 0; nf < 2; ++nf)
#pragma unroll
        for (int r = 0; r < 16; ++r) {
          int kvg = kv0 + nf * 32 + (r & 3) + 8 * (r >> 2) + 4 * lh;
          if (kvg > qg) sf[nf][r] = -1e30f;
        }
    }

    float tm = sf[0][0];
#pragma unroll
    for (int r = 1; r < 16; ++r) tm = fmaxf(tm, sf[0][r]);
#pragma unroll
    for (int r = 0; r < 16; ++r) tm = fmaxf(tm, sf[1][r]);
    tm = fmaxf(tm, __shfl_xor(tm, 32));
    const float mn = fmaxf(m, tm);
    const float corr = __expf(m - mn);
    m = mn;
    float rs = 0.f;
#pragma unroll
    for (int nf = 0; nf < 2; ++nf)
#pragma unroll
      for (int r = 0; r < 16; ++r) {
        float p = __expf(sf[nf][r] - mn);
        sf[nf][r] = p;
        rs += p;
      }
    rs += __shfl_xor(rs, 32);
    l = l * corr + rs;
#pragma unroll
    for (int mo = 0; mo < 2; ++mo)
#pragma unroll
      for (int r = 0; r < 16; ++r) acc[mo][r] *= corr;

    u32 q32[2][8];
#pragma unroll
    for (int nf = 0; nf < 2; ++nf)
#pragma unroll
      for (int i = 0; i < 8; ++i)
        asm("v_cvt_pk_bf16_f32 %0, %1, %2"
            : "=v"(q32[nf][i]) : "v"(sf[nf][2 * i]), "v"(sf[nf][2 * i + 1]));

#pragma unroll
    for (int s = 0; s < 4; ++s) {
      const int nfp = s >> 1, sg = s & 1;
      u32 x = q32[nfp][4 * sg + 0];
      u32 y = q32[nfp][4 * sg + 1];
      u32 z = q32[nfp][4 * sg + 2];
      u32 w = q32[nfp][4 * sg + 3];
      asm("v_permlane32_swap_b32 %0, %1" : "+v"(x), "+v"(z));
      asm("v_permlane32_swap_b32 %0, %1" : "+v"(y), "+v"(w));
      U pb;
      pb.u = (u32x4){x, y, z, w};
#pragma unroll
      for (int mo = 0; mo < 2; ++mo) {
        int r = mo * 32 + lq;
        int c = s * 2 + lh;
        U vv;
        vv.u = *(const u32x4*)(Vs + r * 64 + ((c ^ (r & 7)) << 3));
        acc[mo] = __builtin_amdgcn_mfma_f32_32x32x16_bf16(vv.b, pb.b, acc[mo], 0, 0, 0);
      }
    }
  }

  __syncthreads();
  u16* Ow = lds + wid * (32 * 72);
  const float inv = 1.f / l;
#pragma unroll
  for (int mo = 0; mo < 2; ++mo)
#pragma unroll
    for (int r = 0; r < 16; ++r) {
      int d = mo * 32 + (r & 3) + 8 * (r >> 2) + 4 * lh;
      Ow[lq * 72 + d] = f2bf(acc[mo][r] * inv);
    }
  __asm__ volatile("" ::: "memory");
#pragma unroll
  for (int r4 = 0; r4 < 4; ++r4) {
    int ql = r4 * 8 + (lane >> 3);
    int c = lane & 7;
    u32x4 v = *(const u32x4*)(Ow + ql * 72 + c * 8);
    *(u32x4*)(mid + (size_t)(b * S_ + q0w + ql) * H_ + h * HD + c * 8) = v;
  }
}

// ---------------- fused residual + LayerNorm ----------------
template<int BF16OUT>
__global__ __launch_bounds__(256) void k_ln(const float* __restrict__ a,
                                            const float* __restrict__ r,
                                            const float* __restrict__ g,
                                            const float* __restrict__ bb,
                                            float* __restrict__ outf,
                                            u16* __restrict__ outb) {
  __shared__ float red[8];
  const int row = blockIdx.x, tid = threadIdx.x;
  const size_t base = (size_t)row * H_ + tid * 4;
  f32x4 va = *(const f32x4*)(a + base);
  f32x4 vr = *(const f32x4*)(r + base);
  f32x4 t = va + vr;
  float sum = t[0] + t[1] + t[2] + t[3];
#pragma unroll
  for (int msk = 32; msk >= 1; msk >>= 1) sum += __shfl_xor(sum, msk, 64);
  if ((tid & 63) == 0) red[tid >> 6] = sum;
  __syncthreads();
  float mu = (red[0] + red[1] + red[2] + red[3]) * (1.f / H_);
  f32x4 d = t - mu;
  float sq = d[0] * d[0] + d[1] * d[1] + d[2] * d[2] + d[3] * d[3];
#pragma unroll
  for (int msk = 32; msk >= 1; msk >>= 1) sq += __shfl_xor(sq, msk, 64);
  if ((tid & 63) == 0) red[4 + (tid >> 6)] = sq;
  __syncthreads();
  float var = (red[4] + red[5] + red[6] + red[7]) * (1.f / H_);
  float rs = rsqrtf(var + LN_EPS);
  f32x4 gg = *(const f32x4*)(g + tid * 4);
  f32x4 bv = *(const f32x4*)(bb + tid * 4);
  f32x4 o = d * rs * gg + bv;
  *(f32x4*)(outf + base) = o;
  if (BF16OUT) {
    u16x4 ob = { f2bf(o[0]), f2bf(o[1]), f2bf(o[2]), f2bf(o[3]) };
    *(u16x4*)(outb + base) = ob;
  }
}

// ------- LN2 with split-K reduce: out = LN(h + sum_z P[z] + bdn) -------
__global__ __launch_bounds__(256) void k_lnr(const float* __restrict__ a,
                                             const u16* __restrict__ P,
                                             const float* __restrict__ bd,
                                             const float* __restrict__ g,
                                             const float* __restrict__ bb,
                                             float* __restrict__ outf) {
  __shared__ float red[8];
  const int row = blockIdx.x, tid = threadIdx.x;
  const size_t base = (size_t)row * H_ + tid * 4;
  f32x4 t = *(const f32x4*)(a + base);
  f32x4 vb = *(const f32x4*)(bd + tid * 4);
  t += vb;
#pragma unroll
  for (int z = 0; z < 4; ++z) {
    u16x4 p = *(const u16x4*)(P + (size_t)z * ((size_t)B_ * S_ * H_) + base);
#pragma unroll
    for (int e = 0; e < 4; ++e) t[e] += __uint_as_float((u32)p[e] << 16);
  }
  float sum = t[0] + t[1] + t[2] + t[3];
#pragma unroll
  for (int msk = 32; msk >= 1; msk >>= 1) sum += __shfl_xor(sum, msk, 64);
  if ((tid & 63) == 0) red[tid >> 6] = sum;
  __syncthreads();
  float mu = (red[0] + red[1] + red[2] + red[3]) * (1.f / H_);
  f32x4 d = t - mu;
  float sq = d[0] * d[0] + d[1] * d[1] + d[2] * d[2] + d[3] * d[3];
#pragma unroll
  for (int msk = 32; msk >= 1; msk >>= 1) sq += __shfl_xor(sq, msk, 64);
  if ((tid & 63) == 0) red[4 + (tid >> 6)] = sq;
  __syncthreads();
  float var = (red[4] + red[5] + red[6] + red[7]) * (1.f / H_);
  float rs = rsqrtf(var + LN_EPS);
  f32x4 gg = *(const f32x4*)(g + tid * 4);
  f32x4 bv = *(const f32x4*)(bb + tid * 4);
  f32x4 o = d * rs * gg + bv;
  *(f32x4*)(outf + base) = o;
}

// ---------------- host launcher ----------------
extern "C" void kernel_launch(void* const* d_in, const int* in_sizes, int n_in,
                              void* d_out, int out_size, void* d_ws, size_t ws_size,
                              hipStream_t stream) {
  const float* X   = (const float*)d_in[0];
  const float* Wq  = (const float*)d_in[1];
  const float* bq  = (const float*)d_in[2];
  const float* Wk  = (const float*)d_in[3];
  const float* bk  = (const float*)d_in[4];
  const float* Wv  = (const float*)d_in[5];
  const float* bv  = (const float*)d_in[6];
  const float* Wo  = (const float*)d_in[7];
  const float* bo  = (const float*)d_in[8];
  const float* g1  = (const float*)d_in[9];
  const float* b1  = (const float*)d_in[10];
  const float* Wup = (const float*)d_in[11];
  const float* bup = (const float*)d_in[12];
  const float* Wdn = (const float*)d_in[13];
  const float* bdn = (const float*)d_in[14];
  const float* g2  = (const float*)d_in[15];
  const float* b2  = (const float*)d_in[16];
  float* out = (float*)d_out;

  const size_t MS = (size_t)B_ * S_;   // 4096
  const size_t nX = MS * H_;           // 4,194,304

  char* ws = (char*)d_ws;
  size_t off = 0;
  auto alloc = [&](size_t bytes) {
    char* p = ws + off;
    off += (bytes + 255) & ~(size_t)255;
    return p;
  };
  u16* Xb    = (u16*)alloc(nX * 2);                    // 8MB   (h alias start)
  u16* Wqkv  = (u16*)alloc((size_t)3 * H_ * H_ * 2);   // 6MB
  u16* Wob   = (u16*)alloc((size_t)H_ * H_ * 2);       // 2MB   (h = 16MB over these 3)
  u16* Wupb  = (u16*)alloc((size_t)4 * H_ * H_ * 2);   // 8MB
  u16* Wdnb  = (u16*)alloc((size_t)4 * H_ * H_ * 2);   // 8MB
  float* bqkv = (float*)alloc(3 * H_ * 4);             // 12KB
  u16* QKVb  = (u16*)alloc(nX * 3 * 2);                // 24MB  (upb alias start)
  u16* midb  = (u16*)alloc(nX * 2);                    // 8MB
  u16* Pbuf  = (u16*)alloc(nX * 4 * 2);                // 32MB: vtb / att / hb / P
  // aliases (producer strictly after old consumers in stream order):
  float* h   = (float*)Xb;        // 16MB (Xb+Wqkv+Wob dead after QKV/Wo GEMMs)
  u16* upb   = QKVb;              // 32MB (QKVb+midb dead after attn / Wo-GEMM)
  u16* vtb   = Pbuf;              // 8MB  (dead after attn)
  float* att = (float*)Pbuf;      // 16MB f32 Wo out (dead after LN1)
  u16* hb    = Pbuf + nX * 2;     // 8MB bf16 h (dead after up-GEMM)
  u16* P     = Pbuf;              // 4 x 8MB bf16 down partials (after all above dead)

  dim3 blk(256);

  k_cvt<<<dim3(4096), blk, 0, stream>>>(X, Xb, (int)(nX / 4));
  k_cvt<<<dim3(1024), blk, 0, stream>>>(Wq, Wqkv, H_ * H_ / 4);
  k_cvt<<<dim3(1024), blk, 0, stream>>>(Wk, Wqkv + (size_t)H_ * H_, H_ * H_ / 4);
  k_cvt<<<dim3(1024), blk, 0, stream>>>(Wv, Wqkv + (size_t)2 * H_ * H_, H_ * H_ / 4);
  k_cvt<<<dim3(1024), blk, 0, stream>>>(Wo, Wob, H_ * H_ / 4);
  k_cvt<<<dim3(4096), blk, 0, stream>>>(Wup, Wupb, 4 * H_ * H_ / 4);
  k_cvt<<<dim3(4096), blk, 0, stream>>>(Wdn, Wdnb, 4 * H_ * H_ / 4);
  k_pack3<<<dim3(12), blk, 0, stream>>>(bq, bk, bv, bqkv);

  // fused QKV projection [4096,3072], 8-phase 256^2: grid 16*12 = 192
  k_gemm8<0, 0, 1, 1><<<dim3(16 * 12), dim3(512), 131072, stream>>>(
      Xb, Wqkv, bqkv, nullptr, QKVb, (int)MS, 3 * H_, H_, H_, H_, 16);

  k_vt<<<dim3(S_ / 64, B_ * NH), blk, 0, stream>>>(QKVb, vtb);

  k_attn_mfma<<<dim3(S_ / 128, B_ * NH), blk, 0, stream>>>(QKVb, vtb, midb);

  // output projection (legacy 128^2) -> att f32
  k_gemm<0, 1, 0><<<dim3(H_ / 128, MS / 128), blk, 0, stream>>>(
      midb, Wob, bo, att, nullptr, (int)MS, H_, H_);

  // LN1: h = LN(X + att)
  k_ln<1><<<dim3(MS), blk, 0, stream>>>(X, att, g1, b1, h, hb);

  // MLP up [4096,4096] ReLU, 8-phase: grid 16*16 = 256
  k_gemm8<1, 0, 1, 1><<<dim3(16 * 16), dim3(512), 131072, stream>>>(
      hb, Wupb, bup, nullptr, upb, (int)MS, 4 * H_, H_, H_, H_, 16);

  // MLP down split-K=4, bf16 partials -> P[4][4096*1024]: grid 16*4*4 = 256
  k_gemm8<0, 0, 1, 0><<<dim3(16 * 4 * 4), dim3(512), 131072, stream>>>(
      upb, Wdnb, nullptr, nullptr, P, (int)MS, H_, 4 * H_, 4 * H_, H_, 16);

  // LN2 + split-K reduce -> out
  k_lnr<<<dim3(MS), blk, 0, stream>>>(h, P, bdn, g2, b2, out);
}